// Round 1
// baseline (372.937 us; speedup 1.0000x reference)
//
#include <hip/hip_runtime.h>
#include <hip/hip_bf16.h>

// Residual_Comb_Conv: B=2048, C_IN=64, C_MID=64, C_OUT=128, R=60, K=13
// R7: R6 structure, but gemm2 rewritten LDS-free:
//  - Both MFMA operands are contiguous 16B/lane in global memory already
//    (W23t rows are K-major; z2T/z3T are [r][b][c] with c contiguous), so
//    each fragment is a direct coalesced global_load_dwordx4.
//  - No LDS, no __syncthreads in the K-loop -> no 2-phase barrier drain.
//  - __launch_bounds__(256,4): VGPR<=128 -> 4 blocks/CU, entire 960-block
//    grid co-resident; latency hidden by 16 waves/CU TLP.
//  - W23t (416 KB) and per-btile z-panels stay L2-resident per XCD thanks to
//    the bid%8 = btile%8 swizzle (unchanged).

typedef __attribute__((ext_vector_type(8))) short bf16x8;
typedef __attribute__((ext_vector_type(4))) float f32x4;
typedef __attribute__((ext_vector_type(4))) unsigned short us4;
typedef __attribute__((ext_vector_type(8))) unsigned short us8;

#define EPSV 1e-5f
#define PLANE 131072           // 2048*64 shorts per z plane
#define ZTOT  7864320          // 60*PLANE

__device__ __forceinline__ unsigned short f2bf(float f) {
  unsigned int u = __builtin_bit_cast(unsigned int, f);
  u += 0x7FFFu + ((u >> 16) & 1u);   // round-to-nearest-even
  return (unsigned short)(u >> 16);
}
__device__ __forceinline__ float bf2f(unsigned short s) {
  unsigned int u = ((unsigned int)s) << 16;
  return __builtin_bit_cast(float, u);
}

// ---- prep: weights -> bf16 transposed layouts; last block also folds BN params
// params: [a1|b1|a3|b3|a2|b2p] (6*64) + cc (128) = 512 floats
__global__ void prep_w(const float* __restrict__ W1, const float* __restrict__ W2,
                       const float* __restrict__ W3,
                       const float* __restrict__ g1, const float* __restrict__ be1,
                       const float* __restrict__ mu1, const float* __restrict__ va1,
                       const float* __restrict__ c1,
                       const float* __restrict__ g2, const float* __restrict__ be2,
                       const float* __restrict__ mu2, const float* __restrict__ va2,
                       const float* __restrict__ c2,
                       const float* __restrict__ g3, const float* __restrict__ be3,
                       const float* __restrict__ mu3, const float* __restrict__ va3,
                       const float* __restrict__ c3,
                       unsigned short* __restrict__ W1t,
                       unsigned short* __restrict__ W23t,
                       float* __restrict__ params) {
  int t = blockIdx.x * 256 + threadIdx.x;
  if (t < 4096) {                        // W1: 64*64 (o,c) rows
    int o = t >> 6, c = t & 63;
    const float* src = W1 + (o * 64 + c) * 13;
    unsigned short* dst = W1t + o * 832 + c;
    #pragma unroll
    for (int ks = 0; ks < 13; ks++) dst[ks * 64] = f2bf(src[ks]);
  } else if (t < 20480) {                // W2,W3: 2*128*64 rows
    int idx = t - 4096;
    int half = idx >> 13;                // 0 -> W2, 1 -> W3
    int o = (idx >> 6) & 127, c = idx & 63;
    const float* src = (half ? W3 : W2) + (o * 64 + c) * 13;
    unsigned short* dst = W23t + o * 1664 + half * 13 * 64 + c;
    #pragma unroll
    for (int ks = 0; ks < 13; ks++) dst[ks * 64] = f2bf(src[ks]);
  }
  if (blockIdx.x == 79) {
    int u = threadIdx.x;
    if (u < 64) {
      float a1v = g1[u] * rsqrtf(va1[u] + EPSV);
      params[u]       = a1v;
      params[64 + u]  = be1[u] - mu1[u] * a1v;
      float a3v = g3[u] * rsqrtf(va3[u] + EPSV);
      params[128 + u] = a3v;
      params[192 + u] = be3[u] - mu3[u] * a3v;
      float a2v = g2[u] * rsqrtf(va2[u] + EPSV);
      params[256 + u] = a2v;
      params[320 + u] = be2[u] - mu2[u] * a2v + a2v * c1[u];  // fold conv1 bias
    }
    if (u < 128) params[384 + u] = c2[u] + c3[u];
  }
}

// ---- transpose-in: x[b][c][r] f32 -> z1T/z3T[r][b][c] bf16 with act1/act3
__global__ __launch_bounds__(256) void t_in(const float* __restrict__ x,
                                            const float* __restrict__ params,
                                            unsigned short* __restrict__ z1T,
                                            unsigned short* __restrict__ z3T) {
  __shared__ float xt[64 * 61];
  __shared__ float prm[256];
  const int b = blockIdx.x, t = threadIdx.x;
  prm[t] = params[t];                       // a1|b1|a3|b3
  for (int i = t; i < 3840; i += 256) {
    int c = i / 60;
    xt[c * 61 + (i - c * 60)] = x[b * 3840 + i];
  }
  __syncthreads();
  if (t < 240) {
    int r = t >> 2, g = t & 3, c0 = g << 4;
    us8 z1v0, z1v1, z3v0, z3v1;
    #pragma unroll
    for (int j = 0; j < 8; j++) {
      int c = c0 + j;
      float v = xt[c * 61 + r];
      z1v0[j] = f2bf(fmaxf(fmaf(v, prm[c], prm[64 + c]), 0.f));
      z3v0[j] = f2bf(fmaxf(fmaf(v, prm[128 + c], prm[192 + c]), 0.f));
    }
    #pragma unroll
    for (int j = 0; j < 8; j++) {
      int c = c0 + 8 + j;
      float v = xt[c * 61 + r];
      z1v1[j] = f2bf(fmaxf(fmaf(v, prm[c], prm[64 + c]), 0.f));
      z3v1[j] = f2bf(fmaxf(fmaf(v, prm[128 + c], prm[192 + c]), 0.f));
    }
    int idx = (r * 2048 + b) * 64 + c0;
    *(us8*)(z1T + idx) = z1v0;  *(us8*)(z1T + idx + 8) = z1v1;
    *(us8*)(z3T + idx) = z3v0;  *(us8*)(z3T + idx + 8) = z3v1;
  }
}

#define MFMA __builtin_amdgcn_mfma_f32_16x16x32_bf16

// ---- gemm1: block = (btile=128 batches, r-pair). C[64 x 128] for each of 2 r's.
//      A (W1t) staged once, shared. Waves: (rsel = w>>1, nhh = w&1); wave tile
//      64 rows x 64 cols = 4m x 4n of 16x16x32.
__global__ __launch_bounds__(256, 2) void gemm1(const unsigned short* __restrict__ W1t,
                                                const unsigned short* __restrict__ z1T,
                                                const int* __restrict__ nei,
                                                const float* __restrict__ params,
                                                unsigned short* __restrict__ z2T) {
  __shared__ unsigned short As[2][4096];        // 64 x 64 per buf
  __shared__ unsigned short Bs[2][2][8192];     // [buf][r] 128 x 64

  const int bid = blockIdx.x;
  const int rp = bid >> 4, btile = bid & 15;    // bid%8 = btile%8 -> XCD locality
  const int b0 = btile << 7;
  const int rA = rp * 2, rB = rA + 1;
  const int t = threadIdx.x, wave = t >> 6, lane = t & 63;
  const int quad = lane >> 4, nl = lane & 15;
  const int rsel = wave >> 1, nhh = wave & 1;

  int pl0[13], pl1[13];
  #pragma unroll
  for (int q = 0; q < 13; q++) { pl0[q] = nei[rA * 13 + q]; pl1[q] = nei[rB * 13 + q]; }

  const int trow = t >> 3, tj = t & 7;
  const int sw8 = ((tj ^ (trow & 7)) << 3);     // XOR-swizzled chunk (shorts)
  const unsigned short* gA = W1t + trow * 832 + tj * 8;
  const unsigned short* gB = z1T + (b0 + trow) * 64 + tj * 8;
  unsigned short* lA = &As[0][trow * 64 + sw8];
  unsigned short* lB0 = &Bs[0][0][trow * 64 + sw8];
  unsigned short* lB1 = &Bs[0][1][trow * 64 + sw8];

  // stage kq=0 into buffer 0
  {
    us8 va0 = *(const us8*)(gA);
    us8 va1 = *(const us8*)(gA + 32 * 832);
    const unsigned short* g0 = gB + pl0[0] * PLANE;
    const unsigned short* g1p = gB + pl1[0] * PLANE;
    us8 b00 = *(const us8*)(g0);
    us8 b01 = *(const us8*)(g0 + 2048);
    us8 b02 = *(const us8*)(g0 + 4096);
    us8 b03 = *(const us8*)(g0 + 6144);
    us8 b10 = *(const us8*)(g1p);
    us8 b11 = *(const us8*)(g1p + 2048);
    us8 b12 = *(const us8*)(g1p + 4096);
    us8 b13 = *(const us8*)(g1p + 6144);
    *(us8*)(lA) = va0;  *(us8*)(lA + 2048) = va1;
    *(us8*)(lB0) = b00; *(us8*)(lB0 + 2048) = b01;
    *(us8*)(lB0 + 4096) = b02; *(us8*)(lB0 + 6144) = b03;
    *(us8*)(lB1) = b10; *(us8*)(lB1 + 2048) = b11;
    *(us8*)(lB1 + 4096) = b12; *(us8*)(lB1 + 6144) = b13;
  }
  __syncthreads();

  const int c0 = ((quad ^ (nl & 7)) << 3);      // physical chunk for logical quad
  f32x4 acc[4][4] = {};
  #pragma unroll 1
  for (int kq = 0; kq < 13; kq++) {
    const int bf = kq & 1;
    us8 va0, va1, b00, b01, b02, b03, b10, b11, b12, b13;
    if (kq < 12) {
      const unsigned short* ga = gA + (kq + 1) * 64;
      va0 = *(const us8*)(ga);
      va1 = *(const us8*)(ga + 32 * 832);
      const unsigned short* g0 = gB + pl0[kq + 1] * PLANE;
      const unsigned short* g1p = gB + pl1[kq + 1] * PLANE;
      b00 = *(const us8*)(g0);        b01 = *(const us8*)(g0 + 2048);
      b02 = *(const us8*)(g0 + 4096); b03 = *(const us8*)(g0 + 6144);
      b10 = *(const us8*)(g1p);        b11 = *(const us8*)(g1p + 2048);
      b12 = *(const us8*)(g1p + 4096); b13 = *(const us8*)(g1p + 6144);
    }
    const unsigned short* Ab = &As[bf][nl * 64];
    const unsigned short* Bb = &Bs[bf][rsel][(nhh * 64 + nl) * 64];
    bf16x8 af[4][2], bfr[4][2];
    #pragma unroll
    for (int mt = 0; mt < 4; mt++) {
      af[mt][0] = *(const bf16x8*)(Ab + mt * 1024 + c0);
      af[mt][1] = *(const bf16x8*)(Ab + mt * 1024 + (c0 ^ 32));
    }
    #pragma unroll
    for (int nt = 0; nt < 4; nt++) {
      bfr[nt][0] = *(const bf16x8*)(Bb + nt * 1024 + c0);
      bfr[nt][1] = *(const bf16x8*)(Bb + nt * 1024 + (c0 ^ 32));
    }
    #pragma unroll
    for (int h = 0; h < 2; h++)
      #pragma unroll
      for (int mt = 0; mt < 4; mt++)
        #pragma unroll
        for (int nt = 0; nt < 4; nt++)
          acc[mt][nt] = MFMA(af[mt][h], bfr[nt][h], acc[mt][nt], 0, 0, 0);
    if (kq < 12) {
      unsigned short* la = lA + (bf ^ 1) * 4096;
      unsigned short* l0 = lB0 + (bf ^ 1) * 16384;
      unsigned short* l1 = lB1 + (bf ^ 1) * 16384;
      *(us8*)(la) = va0;  *(us8*)(la + 2048) = va1;
      *(us8*)(l0) = b00; *(us8*)(l0 + 2048) = b01;
      *(us8*)(l0 + 4096) = b02; *(us8*)(l0 + 6144) = b03;
      *(us8*)(l1) = b10; *(us8*)(l1 + 2048) = b11;
      *(us8*)(l1 + 4096) = b12; *(us8*)(l1 + 6144) = b13;
    }
    __syncthreads();
  }

  // epilogue: act2 -> z2T[r][b][o]
  const int rr = rA + rsel;
  #pragma unroll
  for (int mt = 0; mt < 4; mt++) {
    int ob = mt * 16 + quad * 4;
    f32x4 av = *(const f32x4*)(params + 256 + ob);
    f32x4 bv = *(const f32x4*)(params + 320 + ob);
    #pragma unroll
    for (int nt = 0; nt < 4; nt++) {
      int col = b0 + nhh * 64 + nt * 16 + nl;
      f32x4 a = acc[mt][nt];
      us4 w;
      w.x = f2bf(fmaxf(fmaf(a[0], av[0], bv[0]), 0.f));
      w.y = f2bf(fmaxf(fmaf(a[1], av[1], bv[1]), 0.f));
      w.z = f2bf(fmaxf(fmaf(a[2], av[2], bv[2]), 0.f));
      w.w = f2bf(fmaxf(fmaf(a[3], av[3], bv[3]), 0.f));
      *(us4*)(z2T + (rr * 2048 + col) * 64 + ob) = w;
    }
  }
}

// ---- gemm2: LDS-free. block = (btile=128, r): C[128 x 128] = W23t . [z2|z3]
//      waves: (mh = w>>1, nh = w&1), wave tile 64 x 64 = 4m x 4n of 16x16x32.
//      Every fragment is a direct coalesced 16B/lane global load:
//        A(mt,h) = W23t[(mh*64+mt*16+nl)*1664 + kq*64 + quad*8 + h*32]
//        B(nt,h) = plane[(b0+nh*64+nt*16+nl)*64 + quad*8 + h*32]
//      No LDS, no barriers; grid fully co-resident at 4 blocks/CU.
__global__ __launch_bounds__(256, 4) void gemm2(const unsigned short* __restrict__ W23t,
                                                const unsigned short* __restrict__ z2T,
                                                const unsigned short* __restrict__ z3T,
                                                const int* __restrict__ nei,
                                                const float* __restrict__ params,
                                                unsigned short* __restrict__ outT) {
  const int bid = blockIdx.x;
  const int r = bid >> 4, btile = bid & 15;  // bid%8 = btile%8 -> XCD locality
  const int b0 = btile << 7;
  const int t = threadIdx.x, wave = t >> 6, lane = t & 63;
  const int quad = lane >> 4, nl = lane & 15;
  const int mh = wave >> 1, nh = wave & 1;

  int pl[13];
  #pragma unroll
  for (int q = 0; q < 13; q++) pl[q] = nei[r * 13 + q];

  // per-lane fragment bases
  const unsigned short* Abase = W23t + (mh * 64 + nl) * 1664 + quad * 8;
  const int Boff = (b0 + nh * 64 + nl) * 64 + quad * 8;

  f32x4 acc[4][4] = {};
  #pragma unroll 1
  for (int kq = 0; kq < 26; kq++) {
    const unsigned short* Ak = Abase + kq * 64;
    const unsigned short* Bk = (kq < 13 ? z2T + pl[kq] * PLANE
                                        : z3T + pl[kq - 13] * PLANE) + Boff;
    #pragma unroll
    for (int h = 0; h < 2; h++) {
      bf16x8 af[4], bfr[4];
      #pragma unroll
      for (int mt = 0; mt < 4; mt++)
        af[mt] = *(const bf16x8*)(Ak + mt * 26624 + h * 32);   // mt*16 rows * 1664
      #pragma unroll
      for (int nt = 0; nt < 4; nt++)
        bfr[nt] = *(const bf16x8*)(Bk + nt * 1024 + h * 32);   // nt*16 cols * 64
      #pragma unroll
      for (int mt = 0; mt < 4; mt++)
        #pragma unroll
        for (int nt = 0; nt < 4; nt++)
          acc[mt][nt] = MFMA(af[mt], bfr[nt], acc[mt][nt], 0, 0, 0);
    }
  }

  // epilogue: + cc -> outT[r][b][o] bf16
  #pragma unroll
  for (int mt = 0; mt < 4; mt++) {
    int ob = mh * 64 + mt * 16 + quad * 4;
    f32x4 cv = *(const f32x4*)(params + 384 + ob);
    #pragma unroll
    for (int nt = 0; nt < 4; nt++) {
      int col = b0 + nh * 64 + nt * 16 + nl;
      f32x4 a = acc[mt][nt];
      us4 w;
      w.x = f2bf(a[0] + cv[0]);
      w.y = f2bf(a[1] + cv[1]);
      w.z = f2bf(a[2] + cv[2]);
      w.w = f2bf(a[3] + cv[3]);
      *(us4*)(outT + (r * 2048 + col) * 128 + ob) = w;
    }
  }
}

// ---- transpose-out: outT[r][b][o] bf16 -> out[b][o][r] f32
__global__ __launch_bounds__(256) void t_out(const unsigned short* __restrict__ outT,
                                             float* __restrict__ out) {
  __shared__ float ot[60 * 129];
  const int b = blockIdx.x, t = threadIdx.x;
  for (int i = t; i < 1920; i += 256) {
    int r = i >> 5, og = (i & 31) << 2;
    us4 v = *(const us4*)(outT + (r * 2048 + b) * 128 + og);
    ot[r * 129 + og + 0] = bf2f(v.x);
    ot[r * 129 + og + 1] = bf2f(v.y);
    ot[r * 129 + og + 2] = bf2f(v.z);
    ot[r * 129 + og + 3] = bf2f(v.w);
  }
  __syncthreads();
  int o = t >> 1, s = t & 1;
  float* dst = out + b * 7680 + o * 60 + s * 30;
  #pragma unroll
  for (int j = 0; j < 30; j++) dst[j] = ot[(s * 30 + j) * 129 + o];
}

extern "C" void kernel_launch(void* const* d_in, const int* in_sizes, int n_in,
                              void* d_out, int out_size, void* d_ws, size_t ws_size,
                              hipStream_t stream) {
  const float* x   = (const float*)d_in[0];
  const int*   nei = (const int*)d_in[1];
  const float* g1  = (const float*)d_in[2];
  const float* be1 = (const float*)d_in[3];
  const float* mu1 = (const float*)d_in[4];
  const float* va1 = (const float*)d_in[5];
  const float* W1  = (const float*)d_in[6];
  const float* c1  = (const float*)d_in[7];
  const float* g2  = (const float*)d_in[8];
  const float* be2 = (const float*)d_in[9];
  const float* mu2 = (const float*)d_in[10];
  const float* va2 = (const float*)d_in[11];
  const float* W2  = (const float*)d_in[12];
  const float* c2  = (const float*)d_in[13];
  const float* g3  = (const float*)d_in[14];
  const float* be3 = (const float*)d_in[15];
  const float* mu3 = (const float*)d_in[16];
  const float* va3 = (const float*)d_in[17];
  const float* W3  = (const float*)d_in[18];
  const float* c3  = (const float*)d_in[19];

  // ws layout (63.5 MB): W1t | W23t | params | z2T | z3T | big(z1T ∪ outT)
  unsigned short* W1t  = (unsigned short*)d_ws;
  unsigned short* W23t = W1t + 53248;
  float*          prm  = (float*)(W23t + 212992);
  unsigned short* z2T  = (unsigned short*)(prm + 512);
  unsigned short* z3T  = z2T + ZTOT;
  unsigned short* big  = z3T + ZTOT;       // z1T (read in gemm1) aliases outT (written in gemm2)
  unsigned short* z1T  = big;
  unsigned short* outT = big;

  prep_w<<<80, 256, 0, stream>>>(W1, W2, W3,
                                 g1, be1, mu1, va1, c1,
                                 g2, be2, mu2, va2, c2,
                                 g3, be3, mu3, va3, c3,
                                 W1t, W23t, prm);
  t_in<<<2048, 256, 0, stream>>>(x, prm, z1T, z3T);
  gemm1<<<480, 256, 0, stream>>>(W1t, z1T, nei, prm, z2T);
  gemm2<<<960, 256, 0, stream>>>(W23t, z2T, z3T, nei, prm, outT);
  t_out<<<2048, 256, 0, stream>>>(outT, (float*)d_out);
}

// Round 2
// 265.825 us; speedup vs baseline: 1.4029x; 1.4029x over previous
//
#include <hip/hip_runtime.h>
#include <hip/hip_bf16.h>

// Residual_Comb_Conv: B=2048, C_IN=64, C_MID=64, C_OUT=128, R=60, K=13
// R8: gemm2 back to LDS staging (R7 post-mortem: direct global fragment loads
// are latency-bound, 205 us). R6 gemm2 was exactly on the LDS-BW roofline
// (320 KB LDS traffic per CU-round = 3.7k cyc = measured round time), so R8
// cuts LDS bytes/FLOP with a 64x128 wave tile (ratio 32 -> 42.7) and
// global_load_lds staging (no ds_write insts, no staging VGPRs):
//  - block = 4 waves (2mh x 2nh), tile 128 x 256 batches, acc[4][8].
//  - grid 480 = 60 r x 8 btiles; bid%8 = btile -> one btile panel per XCD L2.
//  - LDS 96 KB double-buffered; staging via global_load_lds width=16 with
//    XOR swizzle applied to the per-lane GLOBAL source (linear LDS dest),
//    reads use the same XOR -> bank-conflict-free (verified 0 in R6).
//  - Total gemm2 LDS traffic 4.0 GB -> 1.8 GB.

typedef __attribute__((ext_vector_type(8))) short bf16x8;
typedef __attribute__((ext_vector_type(4))) float f32x4;
typedef __attribute__((ext_vector_type(4))) unsigned short us4;
typedef __attribute__((ext_vector_type(8))) unsigned short us8;

#define EPSV 1e-5f
#define PLANE 131072           // 2048*64 shorts per z plane
#define ZTOT  7864320          // 60*PLANE

__device__ __forceinline__ unsigned short f2bf(float f) {
  unsigned int u = __builtin_bit_cast(unsigned int, f);
  u += 0x7FFFu + ((u >> 16) & 1u);   // round-to-nearest-even
  return (unsigned short)(u >> 16);
}
__device__ __forceinline__ float bf2f(unsigned short s) {
  unsigned int u = ((unsigned int)s) << 16;
  return __builtin_bit_cast(float, u);
}

// async global->LDS, 16B per lane, wave-uniform LDS base + lane*16 linear dest
typedef const __attribute__((address_space(1))) unsigned int gas_u32;
typedef __attribute__((address_space(3))) unsigned int las_u32;
__device__ __forceinline__ void gl16(const void* g, void* l) {
  __builtin_amdgcn_global_load_lds((gas_u32*)g, (las_u32*)l, 16, 0, 0);
}

// ---- prep: weights -> bf16 transposed layouts; last block also folds BN params
// params: [a1|b1|a3|b3|a2|b2p] (6*64) + cc (128) = 512 floats
__global__ void prep_w(const float* __restrict__ W1, const float* __restrict__ W2,
                       const float* __restrict__ W3,
                       const float* __restrict__ g1, const float* __restrict__ be1,
                       const float* __restrict__ mu1, const float* __restrict__ va1,
                       const float* __restrict__ c1,
                       const float* __restrict__ g2, const float* __restrict__ be2,
                       const float* __restrict__ mu2, const float* __restrict__ va2,
                       const float* __restrict__ c2,
                       const float* __restrict__ g3, const float* __restrict__ be3,
                       const float* __restrict__ mu3, const float* __restrict__ va3,
                       const float* __restrict__ c3,
                       unsigned short* __restrict__ W1t,
                       unsigned short* __restrict__ W23t,
                       float* __restrict__ params) {
  int t = blockIdx.x * 256 + threadIdx.x;
  if (t < 4096) {                        // W1: 64*64 (o,c) rows
    int o = t >> 6, c = t & 63;
    const float* src = W1 + (o * 64 + c) * 13;
    unsigned short* dst = W1t + o * 832 + c;
    #pragma unroll
    for (int ks = 0; ks < 13; ks++) dst[ks * 64] = f2bf(src[ks]);
  } else if (t < 20480) {                // W2,W3: 2*128*64 rows
    int idx = t - 4096;
    int half = idx >> 13;                // 0 -> W2, 1 -> W3
    int o = (idx >> 6) & 127, c = idx & 63;
    const float* src = (half ? W3 : W2) + (o * 64 + c) * 13;
    unsigned short* dst = W23t + o * 1664 + half * 13 * 64 + c;
    #pragma unroll
    for (int ks = 0; ks < 13; ks++) dst[ks * 64] = f2bf(src[ks]);
  }
  if (blockIdx.x == 79) {
    int u = threadIdx.x;
    if (u < 64) {
      float a1v = g1[u] * rsqrtf(va1[u] + EPSV);
      params[u]       = a1v;
      params[64 + u]  = be1[u] - mu1[u] * a1v;
      float a3v = g3[u] * rsqrtf(va3[u] + EPSV);
      params[128 + u] = a3v;
      params[192 + u] = be3[u] - mu3[u] * a3v;
      float a2v = g2[u] * rsqrtf(va2[u] + EPSV);
      params[256 + u] = a2v;
      params[320 + u] = be2[u] - mu2[u] * a2v + a2v * c1[u];  // fold conv1 bias
    }
    if (u < 128) params[384 + u] = c2[u] + c3[u];
  }
}

// ---- transpose-in: x[b][c][r] f32 -> z1T/z3T[r][b][c] bf16 with act1/act3
__global__ __launch_bounds__(256) void t_in(const float* __restrict__ x,
                                            const float* __restrict__ params,
                                            unsigned short* __restrict__ z1T,
                                            unsigned short* __restrict__ z3T) {
  __shared__ float xt[64 * 61];
  __shared__ float prm[256];
  const int b = blockIdx.x, t = threadIdx.x;
  prm[t] = params[t];                       // a1|b1|a3|b3
  for (int i = t; i < 3840; i += 256) {
    int c = i / 60;
    xt[c * 61 + (i - c * 60)] = x[b * 3840 + i];
  }
  __syncthreads();
  if (t < 240) {
    int r = t >> 2, g = t & 3, c0 = g << 4;
    us8 z1v0, z1v1, z3v0, z3v1;
    #pragma unroll
    for (int j = 0; j < 8; j++) {
      int c = c0 + j;
      float v = xt[c * 61 + r];
      z1v0[j] = f2bf(fmaxf(fmaf(v, prm[c], prm[64 + c]), 0.f));
      z3v0[j] = f2bf(fmaxf(fmaf(v, prm[128 + c], prm[192 + c]), 0.f));
    }
    #pragma unroll
    for (int j = 0; j < 8; j++) {
      int c = c0 + 8 + j;
      float v = xt[c * 61 + r];
      z1v1[j] = f2bf(fmaxf(fmaf(v, prm[c], prm[64 + c]), 0.f));
      z3v1[j] = f2bf(fmaxf(fmaf(v, prm[128 + c], prm[192 + c]), 0.f));
    }
    int idx = (r * 2048 + b) * 64 + c0;
    *(us8*)(z1T + idx) = z1v0;  *(us8*)(z1T + idx + 8) = z1v1;
    *(us8*)(z3T + idx) = z3v0;  *(us8*)(z3T + idx + 8) = z3v1;
  }
}

#define MFMA __builtin_amdgcn_mfma_f32_16x16x32_bf16

// ---- gemm1: block = (btile=128 batches, r-pair). C[64 x 128] for each of 2 r's.
//      A (W1t) staged once, shared. Waves: (rsel = w>>1, nhh = w&1); wave tile
//      64 rows x 64 cols = 4m x 4n of 16x16x32.
__global__ __launch_bounds__(256, 2) void gemm1(const unsigned short* __restrict__ W1t,
                                                const unsigned short* __restrict__ z1T,
                                                const int* __restrict__ nei,
                                                const float* __restrict__ params,
                                                unsigned short* __restrict__ z2T) {
  __shared__ unsigned short As[2][4096];        // 64 x 64 per buf
  __shared__ unsigned short Bs[2][2][8192];     // [buf][r] 128 x 64

  const int bid = blockIdx.x;
  const int rp = bid >> 4, btile = bid & 15;    // bid%8 = btile%8 -> XCD locality
  const int b0 = btile << 7;
  const int rA = rp * 2, rB = rA + 1;
  const int t = threadIdx.x, wave = t >> 6, lane = t & 63;
  const int quad = lane >> 4, nl = lane & 15;
  const int rsel = wave >> 1, nhh = wave & 1;

  int pl0[13], pl1[13];
  #pragma unroll
  for (int q = 0; q < 13; q++) { pl0[q] = nei[rA * 13 + q]; pl1[q] = nei[rB * 13 + q]; }

  const int trow = t >> 3, tj = t & 7;
  const int sw8 = ((tj ^ (trow & 7)) << 3);     // XOR-swizzled chunk (shorts)
  const unsigned short* gA = W1t + trow * 832 + tj * 8;
  const unsigned short* gB = z1T + (b0 + trow) * 64 + tj * 8;
  unsigned short* lA = &As[0][trow * 64 + sw8];
  unsigned short* lB0 = &Bs[0][0][trow * 64 + sw8];
  unsigned short* lB1 = &Bs[0][1][trow * 64 + sw8];

  // stage kq=0 into buffer 0
  {
    us8 va0 = *(const us8*)(gA);
    us8 va1 = *(const us8*)(gA + 32 * 832);
    const unsigned short* g0 = gB + pl0[0] * PLANE;
    const unsigned short* g1p = gB + pl1[0] * PLANE;
    us8 b00 = *(const us8*)(g0);
    us8 b01 = *(const us8*)(g0 + 2048);
    us8 b02 = *(const us8*)(g0 + 4096);
    us8 b03 = *(const us8*)(g0 + 6144);
    us8 b10 = *(const us8*)(g1p);
    us8 b11 = *(const us8*)(g1p + 2048);
    us8 b12 = *(const us8*)(g1p + 4096);
    us8 b13 = *(const us8*)(g1p + 6144);
    *(us8*)(lA) = va0;  *(us8*)(lA + 2048) = va1;
    *(us8*)(lB0) = b00; *(us8*)(lB0 + 2048) = b01;
    *(us8*)(lB0 + 4096) = b02; *(us8*)(lB0 + 6144) = b03;
    *(us8*)(lB1) = b10; *(us8*)(lB1 + 2048) = b11;
    *(us8*)(lB1 + 4096) = b12; *(us8*)(lB1 + 6144) = b13;
  }
  __syncthreads();

  const int c0 = ((quad ^ (nl & 7)) << 3);      // physical chunk for logical quad
  f32x4 acc[4][4] = {};
  #pragma unroll 1
  for (int kq = 0; kq < 13; kq++) {
    const int bf = kq & 1;
    us8 va0, va1, b00, b01, b02, b03, b10, b11, b12, b13;
    if (kq < 12) {
      const unsigned short* ga = gA + (kq + 1) * 64;
      va0 = *(const us8*)(ga);
      va1 = *(const us8*)(ga + 32 * 832);
      const unsigned short* g0 = gB + pl0[kq + 1] * PLANE;
      const unsigned short* g1p = gB + pl1[kq + 1] * PLANE;
      b00 = *(const us8*)(g0);        b01 = *(const us8*)(g0 + 2048);
      b02 = *(const us8*)(g0 + 4096); b03 = *(const us8*)(g0 + 6144);
      b10 = *(const us8*)(g1p);        b11 = *(const us8*)(g1p + 2048);
      b12 = *(const us8*)(g1p + 4096); b13 = *(const us8*)(g1p + 6144);
    }
    const unsigned short* Ab = &As[bf][nl * 64];
    const unsigned short* Bb = &Bs[bf][rsel][(nhh * 64 + nl) * 64];
    bf16x8 af[4][2], bfr[4][2];
    #pragma unroll
    for (int mt = 0; mt < 4; mt++) {
      af[mt][0] = *(const bf16x8*)(Ab + mt * 1024 + c0);
      af[mt][1] = *(const bf16x8*)(Ab + mt * 1024 + (c0 ^ 32));
    }
    #pragma unroll
    for (int nt = 0; nt < 4; nt++) {
      bfr[nt][0] = *(const bf16x8*)(Bb + nt * 1024 + c0);
      bfr[nt][1] = *(const bf16x8*)(Bb + nt * 1024 + (c0 ^ 32));
    }
    #pragma unroll
    for (int h = 0; h < 2; h++)
      #pragma unroll
      for (int mt = 0; mt < 4; mt++)
        #pragma unroll
        for (int nt = 0; nt < 4; nt++)
          acc[mt][nt] = MFMA(af[mt][h], bfr[nt][h], acc[mt][nt], 0, 0, 0);
    if (kq < 12) {
      unsigned short* la = lA + (bf ^ 1) * 4096;
      unsigned short* l0 = lB0 + (bf ^ 1) * 16384;
      unsigned short* l1 = lB1 + (bf ^ 1) * 16384;
      *(us8*)(la) = va0;  *(us8*)(la + 2048) = va1;
      *(us8*)(l0) = b00; *(us8*)(l0 + 2048) = b01;
      *(us8*)(l0 + 4096) = b02; *(us8*)(l0 + 6144) = b03;
      *(us8*)(l1) = b10; *(us8*)(l1 + 2048) = b11;
      *(us8*)(l1 + 4096) = b12; *(us8*)(l1 + 6144) = b13;
    }
    __syncthreads();
  }

  // epilogue: act2 -> z2T[r][b][o]
  const int rr = rA + rsel;
  #pragma unroll
  for (int mt = 0; mt < 4; mt++) {
    int ob = mt * 16 + quad * 4;
    f32x4 av = *(const f32x4*)(params + 256 + ob);
    f32x4 bv = *(const f32x4*)(params + 320 + ob);
    #pragma unroll
    for (int nt = 0; nt < 4; nt++) {
      int col = b0 + nhh * 64 + nt * 16 + nl;
      f32x4 a = acc[mt][nt];
      us4 w;
      w.x = f2bf(fmaxf(fmaf(a[0], av[0], bv[0]), 0.f));
      w.y = f2bf(fmaxf(fmaf(a[1], av[1], bv[1]), 0.f));
      w.z = f2bf(fmaxf(fmaf(a[2], av[2], bv[2]), 0.f));
      w.w = f2bf(fmaxf(fmaf(a[3], av[3], bv[3]), 0.f));
      *(us4*)(z2T + (rr * 2048 + col) * 64 + ob) = w;
    }
  }
}

// ---- gemm2: block = (btile=256 batches, r): C[128 x 256], 4 waves (2mh x 2nh),
//      wave tile 64 x 128 = 4m x 8n of 16x16x32 (LDS bytes/FLOP cut 1.33x vs
//      64x64) -- plus global_load_lds staging (no ds_writes, no staging VGPRs).
//      LDS layout: linear row-major [row][64]; LDS[row][chunk j] holds global
//      chunk j^(row&7) (swizzle applied on the global source address).
__global__ __launch_bounds__(256, 1) void gemm2(const unsigned short* __restrict__ W23t,
                                                const unsigned short* __restrict__ z2T,
                                                const unsigned short* __restrict__ z3T,
                                                const int* __restrict__ nei,
                                                const float* __restrict__ params,
                                                unsigned short* __restrict__ outT) {
  __shared__ unsigned short As[2][8192];     // 128 x 64 per buf (16 KB)
  __shared__ unsigned short Bs[2][16384];    // 256 x 64 per buf (32 KB)

  const int bid = blockIdx.x;
  const int r = bid >> 3, btile = bid & 7;   // bid%8 = btile -> one btile per XCD
  const int b0 = btile << 8;
  const int t = threadIdx.x, wv = t >> 6, lane = t & 63;
  const int quad = lane >> 4, nl = lane & 15;
  const int mh = wv >> 1, nh = wv & 1;

  // staging geometry: slab = 8 rows x 64 shorts = 1 KB = one gl16 per wave.
  // lane -> (slab-row lr, chunk lj); source chunk pre-swizzled: lj^lr.
  const int lr = lane >> 3, lj = lane & 7;
  const int swz = ((lj ^ lr) << 4);          // byte offset of swizzled 16B chunk
  // A: 16 slabs, wave wv owns slabs 4wv..4wv+3 (rows wv*32..wv*32+31)
  int aoff[4];
  #pragma unroll
  for (int i = 0; i < 4; i++) aoff[i] = (wv * 32 + i * 8 + lr) * 3328 + swz;
  // B: 32 slabs, wave wv owns slabs 8wv..8wv+7 (rows wv*64..wv*64+63)
  int boff[8];
  #pragma unroll
  for (int i = 0; i < 8; i++) boff[i] = (b0 + wv * 64 + i * 8 + lr) * 128 + swz;

  const char* gAb = (const char*)W23t;
  const int neibase = r * 13;

  // stage kq=0 into buffer 0
  {
    int p0 = nei[neibase];
    const char* gb = (const char*)(z2T + p0 * PLANE);
    #pragma unroll
    for (int i = 0; i < 4; i++)
      gl16(gAb + aoff[i], &As[0][(4 * wv + i) * 512]);
    #pragma unroll
    for (int i = 0; i < 8; i++)
      gl16(gb + boff[i], &Bs[0][(8 * wv + i) * 512]);
  }
  asm volatile("s_waitcnt vmcnt(0)" ::: "memory");
  __syncthreads();

  const int c0 = ((quad ^ (nl & 7)) << 3);   // physical chunk (shorts) for h=0
  f32x4 acc[4][8] = {};
  #pragma unroll 1
  for (int kq = 0; kq < 26; kq++) {
    const int buf = kq & 1;
    if (kq < 25) {
      const int kn = kq + 1;
      int p = nei[neibase + (kn < 13 ? kn : kn - 13)];
      const char* ga = gAb + kn * 128;
      const char* gb = (const char*)((kn < 13 ? z2T : z3T) + p * PLANE);
      #pragma unroll
      for (int i = 0; i < 4; i++)
        gl16(ga + aoff[i], &As[buf ^ 1][(4 * wv + i) * 512]);
      #pragma unroll
      for (int i = 0; i < 8; i++)
        gl16(gb + boff[i], &Bs[buf ^ 1][(8 * wv + i) * 512]);
    }
    const unsigned short* Ab = &As[buf][(mh * 64 + nl) * 64];
    const unsigned short* Bb = &Bs[buf][(nh * 128 + nl) * 64];
    #pragma unroll
    for (int h = 0; h < 2; h++) {
      const int cc = h ? (c0 ^ 32) : c0;
      bf16x8 af[4], bfr[8];
      #pragma unroll
      for (int mt = 0; mt < 4; mt++)
        af[mt] = *(const bf16x8*)(Ab + mt * 1024 + cc);
      #pragma unroll
      for (int nt = 0; nt < 8; nt++)
        bfr[nt] = *(const bf16x8*)(Bb + nt * 1024 + cc);
      #pragma unroll
      for (int mt = 0; mt < 4; mt++)
        #pragma unroll
        for (int nt = 0; nt < 8; nt++)
          acc[mt][nt] = MFMA(af[mt], bfr[nt], acc[mt][nt], 0, 0, 0);
    }
    asm volatile("s_waitcnt vmcnt(0)" ::: "memory");
    __syncthreads();
  }

  // epilogue: + cc -> outT[r][b][o] bf16
  #pragma unroll
  for (int mt = 0; mt < 4; mt++) {
    int ob = mh * 64 + mt * 16 + quad * 4;
    f32x4 cv = *(const f32x4*)(params + 384 + ob);
    #pragma unroll
    for (int nt = 0; nt < 8; nt++) {
      int col = b0 + nh * 128 + nt * 16 + nl;
      f32x4 a = acc[mt][nt];
      us4 w;
      w.x = f2bf(a[0] + cv[0]);
      w.y = f2bf(a[1] + cv[1]);
      w.z = f2bf(a[2] + cv[2]);
      w.w = f2bf(a[3] + cv[3]);
      *(us4*)(outT + (r * 2048 + col) * 128 + ob) = w;
    }
  }
}

// ---- transpose-out: outT[r][b][o] bf16 -> out[b][o][r] f32
__global__ __launch_bounds__(256) void t_out(const unsigned short* __restrict__ outT,
                                             float* __restrict__ out) {
  __shared__ float ot[60 * 129];
  const int b = blockIdx.x, t = threadIdx.x;
  for (int i = t; i < 1920; i += 256) {
    int r = i >> 5, og = (i & 31) << 2;
    us4 v = *(const us4*)(outT + (r * 2048 + b) * 128 + og);
    ot[r * 129 + og + 0] = bf2f(v.x);
    ot[r * 129 + og + 1] = bf2f(v.y);
    ot[r * 129 + og + 2] = bf2f(v.z);
    ot[r * 129 + og + 3] = bf2f(v.w);
  }
  __syncthreads();
  int o = t >> 1, s = t & 1;
  float* dst = out + b * 7680 + o * 60 + s * 30;
  #pragma unroll
  for (int j = 0; j < 30; j++) dst[j] = ot[(s * 30 + j) * 129 + o];
}

extern "C" void kernel_launch(void* const* d_in, const int* in_sizes, int n_in,
                              void* d_out, int out_size, void* d_ws, size_t ws_size,
                              hipStream_t stream) {
  const float* x   = (const float*)d_in[0];
  const int*   nei = (const int*)d_in[1];
  const float* g1  = (const float*)d_in[2];
  const float* be1 = (const float*)d_in[3];
  const float* mu1 = (const float*)d_in[4];
  const float* va1 = (const float*)d_in[5];
  const float* W1  = (const float*)d_in[6];
  const float* c1  = (const float*)d_in[7];
  const float* g2  = (const float*)d_in[8];
  const float* be2 = (const float*)d_in[9];
  const float* mu2 = (const float*)d_in[10];
  const float* va2 = (const float*)d_in[11];
  const float* W2  = (const float*)d_in[12];
  const float* c2  = (const float*)d_in[13];
  const float* g3  = (const float*)d_in[14];
  const float* be3 = (const float*)d_in[15];
  const float* mu3 = (const float*)d_in[16];
  const float* va3 = (const float*)d_in[17];
  const float* W3  = (const float*)d_in[18];
  const float* c3  = (const float*)d_in[19];

  // ws layout (63.5 MB): W1t | W23t | params | z2T | z3T | big(z1T ∪ outT)
  unsigned short* W1t  = (unsigned short*)d_ws;
  unsigned short* W23t = W1t + 53248;
  float*          prm  = (float*)(W23t + 212992);
  unsigned short* z2T  = (unsigned short*)(prm + 512);
  unsigned short* z3T  = z2T + ZTOT;
  unsigned short* big  = z3T + ZTOT;       // z1T (read in gemm1) aliases outT (written in gemm2)
  unsigned short* z1T  = big;
  unsigned short* outT = big;

  prep_w<<<80, 256, 0, stream>>>(W1, W2, W3,
                                 g1, be1, mu1, va1, c1,
                                 g2, be2, mu2, va2, c2,
                                 g3, be3, mu3, va3, c3,
                                 W1t, W23t, prm);
  t_in<<<2048, 256, 0, stream>>>(x, prm, z1T, z3T);
  gemm1<<<480, 256, 0, stream>>>(W1t, z1T, nei, prm, z2T);
  gemm2<<<480, 256, 0, stream>>>(W23t, z2T, z3T, nei, prm, outT);
  t_out<<<2048, 256, 0, stream>>>(outT, (float*)d_out);
}

// Round 3
// 244.992 us; speedup vs baseline: 1.5222x; 1.0850x over previous
//
#include <hip/hip_runtime.h>
#include <hip/hip_bf16.h>

// Residual_Comb_Conv: B=2048, C_IN=64, C_MID=64, C_OUT=128, R=60, K=13
// R9: gemm2 = R8's 64x128 wave tile + global_load_lds staging, but BK=32:
//  - LDS per block 48 KB (As[2][128x32] + Bs[2][256x32]) -> 2 blocks/CU
//    co-resident (R8's 96 KB forced 1 block/CU = 1 wave/SIMD = no latency
//    hiding; that was the 92 us regression).
//  - 64 B LDS rows make the b128 fragment read naturally bank-balanced
//    (row parity spreads 16-bank halves, quad spreads chunks) -> no XOR
//    swizzle on either side; one b128 read per K=32 fragment.
//  - 52 K-steps of BK=32; 2-phase schedule (stage next -> compute -> drain),
//    drain covered by the sibling block.

typedef __attribute__((ext_vector_type(8))) short bf16x8;
typedef __attribute__((ext_vector_type(4))) float f32x4;
typedef __attribute__((ext_vector_type(4))) unsigned short us4;
typedef __attribute__((ext_vector_type(8))) unsigned short us8;

#define EPSV 1e-5f
#define PLANE 131072           // 2048*64 shorts per z plane
#define ZTOT  7864320          // 60*PLANE

__device__ __forceinline__ unsigned short f2bf(float f) {
  unsigned int u = __builtin_bit_cast(unsigned int, f);
  u += 0x7FFFu + ((u >> 16) & 1u);   // round-to-nearest-even
  return (unsigned short)(u >> 16);
}
__device__ __forceinline__ float bf2f(unsigned short s) {
  unsigned int u = ((unsigned int)s) << 16;
  return __builtin_bit_cast(float, u);
}

// async global->LDS, 16B per lane, wave-uniform LDS base + lane*16 linear dest
typedef const __attribute__((address_space(1))) unsigned int gas_u32;
typedef __attribute__((address_space(3))) unsigned int las_u32;
__device__ __forceinline__ void gl16(const void* g, void* l) {
  __builtin_amdgcn_global_load_lds((gas_u32*)g, (las_u32*)l, 16, 0, 0);
}

// ---- prep: weights -> bf16 transposed layouts; last block also folds BN params
// params: [a1|b1|a3|b3|a2|b2p] (6*64) + cc (128) = 512 floats
__global__ void prep_w(const float* __restrict__ W1, const float* __restrict__ W2,
                       const float* __restrict__ W3,
                       const float* __restrict__ g1, const float* __restrict__ be1,
                       const float* __restrict__ mu1, const float* __restrict__ va1,
                       const float* __restrict__ c1,
                       const float* __restrict__ g2, const float* __restrict__ be2,
                       const float* __restrict__ mu2, const float* __restrict__ va2,
                       const float* __restrict__ c2,
                       const float* __restrict__ g3, const float* __restrict__ be3,
                       const float* __restrict__ mu3, const float* __restrict__ va3,
                       const float* __restrict__ c3,
                       unsigned short* __restrict__ W1t,
                       unsigned short* __restrict__ W23t,
                       float* __restrict__ params) {
  int t = blockIdx.x * 256 + threadIdx.x;
  if (t < 4096) {                        // W1: 64*64 (o,c) rows
    int o = t >> 6, c = t & 63;
    const float* src = W1 + (o * 64 + c) * 13;
    unsigned short* dst = W1t + o * 832 + c;
    #pragma unroll
    for (int ks = 0; ks < 13; ks++) dst[ks * 64] = f2bf(src[ks]);
  } else if (t < 20480) {                // W2,W3: 2*128*64 rows
    int idx = t - 4096;
    int half = idx >> 13;                // 0 -> W2, 1 -> W3
    int o = (idx >> 6) & 127, c = idx & 63;
    const float* src = (half ? W3 : W2) + (o * 64 + c) * 13;
    unsigned short* dst = W23t + o * 1664 + half * 13 * 64 + c;
    #pragma unroll
    for (int ks = 0; ks < 13; ks++) dst[ks * 64] = f2bf(src[ks]);
  }
  if (blockIdx.x == 79) {
    int u = threadIdx.x;
    if (u < 64) {
      float a1v = g1[u] * rsqrtf(va1[u] + EPSV);
      params[u]       = a1v;
      params[64 + u]  = be1[u] - mu1[u] * a1v;
      float a3v = g3[u] * rsqrtf(va3[u] + EPSV);
      params[128 + u] = a3v;
      params[192 + u] = be3[u] - mu3[u] * a3v;
      float a2v = g2[u] * rsqrtf(va2[u] + EPSV);
      params[256 + u] = a2v;
      params[320 + u] = be2[u] - mu2[u] * a2v + a2v * c1[u];  // fold conv1 bias
    }
    if (u < 128) params[384 + u] = c2[u] + c3[u];
  }
}

// ---- transpose-in: x[b][c][r] f32 -> z1T/z3T[r][b][c] bf16 with act1/act3
__global__ __launch_bounds__(256) void t_in(const float* __restrict__ x,
                                            const float* __restrict__ params,
                                            unsigned short* __restrict__ z1T,
                                            unsigned short* __restrict__ z3T) {
  __shared__ float xt[64 * 61];
  __shared__ float prm[256];
  const int b = blockIdx.x, t = threadIdx.x;
  prm[t] = params[t];                       // a1|b1|a3|b3
  for (int i = t; i < 3840; i += 256) {
    int c = i / 60;
    xt[c * 61 + (i - c * 60)] = x[b * 3840 + i];
  }
  __syncthreads();
  if (t < 240) {
    int r = t >> 2, g = t & 3, c0 = g << 4;
    us8 z1v0, z1v1, z3v0, z3v1;
    #pragma unroll
    for (int j = 0; j < 8; j++) {
      int c = c0 + j;
      float v = xt[c * 61 + r];
      z1v0[j] = f2bf(fmaxf(fmaf(v, prm[c], prm[64 + c]), 0.f));
      z3v0[j] = f2bf(fmaxf(fmaf(v, prm[128 + c], prm[192 + c]), 0.f));
    }
    #pragma unroll
    for (int j = 0; j < 8; j++) {
      int c = c0 + 8 + j;
      float v = xt[c * 61 + r];
      z1v1[j] = f2bf(fmaxf(fmaf(v, prm[c], prm[64 + c]), 0.f));
      z3v1[j] = f2bf(fmaxf(fmaf(v, prm[128 + c], prm[192 + c]), 0.f));
    }
    int idx = (r * 2048 + b) * 64 + c0;
    *(us8*)(z1T + idx) = z1v0;  *(us8*)(z1T + idx + 8) = z1v1;
    *(us8*)(z3T + idx) = z3v0;  *(us8*)(z3T + idx + 8) = z3v1;
  }
}

#define MFMA __builtin_amdgcn_mfma_f32_16x16x32_bf16

// ---- gemm1: block = (btile=128 batches, r-pair). C[64 x 128] for each of 2 r's.
//      A (W1t) staged once, shared. Waves: (rsel = w>>1, nhh = w&1); wave tile
//      64 rows x 64 cols = 4m x 4n of 16x16x32.
__global__ __launch_bounds__(256, 2) void gemm1(const unsigned short* __restrict__ W1t,
                                                const unsigned short* __restrict__ z1T,
                                                const int* __restrict__ nei,
                                                const float* __restrict__ params,
                                                unsigned short* __restrict__ z2T) {
  __shared__ unsigned short As[2][4096];        // 64 x 64 per buf
  __shared__ unsigned short Bs[2][2][8192];     // [buf][r] 128 x 64

  const int bid = blockIdx.x;
  const int rp = bid >> 4, btile = bid & 15;    // bid%8 = btile%8 -> XCD locality
  const int b0 = btile << 7;
  const int rA = rp * 2, rB = rA + 1;
  const int t = threadIdx.x, wave = t >> 6, lane = t & 63;
  const int quad = lane >> 4, nl = lane & 15;
  const int rsel = wave >> 1, nhh = wave & 1;

  int pl0[13], pl1[13];
  #pragma unroll
  for (int q = 0; q < 13; q++) { pl0[q] = nei[rA * 13 + q]; pl1[q] = nei[rB * 13 + q]; }

  const int trow = t >> 3, tj = t & 7;
  const int sw8 = ((tj ^ (trow & 7)) << 3);     // XOR-swizzled chunk (shorts)
  const unsigned short* gA = W1t + trow * 832 + tj * 8;
  const unsigned short* gB = z1T + (b0 + trow) * 64 + tj * 8;
  unsigned short* lA = &As[0][trow * 64 + sw8];
  unsigned short* lB0 = &Bs[0][0][trow * 64 + sw8];
  unsigned short* lB1 = &Bs[0][1][trow * 64 + sw8];

  // stage kq=0 into buffer 0
  {
    us8 va0 = *(const us8*)(gA);
    us8 va1 = *(const us8*)(gA + 32 * 832);
    const unsigned short* g0 = gB + pl0[0] * PLANE;
    const unsigned short* g1p = gB + pl1[0] * PLANE;
    us8 b00 = *(const us8*)(g0);
    us8 b01 = *(const us8*)(g0 + 2048);
    us8 b02 = *(const us8*)(g0 + 4096);
    us8 b03 = *(const us8*)(g0 + 6144);
    us8 b10 = *(const us8*)(g1p);
    us8 b11 = *(const us8*)(g1p + 2048);
    us8 b12 = *(const us8*)(g1p + 4096);
    us8 b13 = *(const us8*)(g1p + 6144);
    *(us8*)(lA) = va0;  *(us8*)(lA + 2048) = va1;
    *(us8*)(lB0) = b00; *(us8*)(lB0 + 2048) = b01;
    *(us8*)(lB0 + 4096) = b02; *(us8*)(lB0 + 6144) = b03;
    *(us8*)(lB1) = b10; *(us8*)(lB1 + 2048) = b11;
    *(us8*)(lB1 + 4096) = b12; *(us8*)(lB1 + 6144) = b13;
  }
  __syncthreads();

  const int c0 = ((quad ^ (nl & 7)) << 3);      // physical chunk for logical quad
  f32x4 acc[4][4] = {};
  #pragma unroll 1
  for (int kq = 0; kq < 13; kq++) {
    const int bf = kq & 1;
    us8 va0, va1, b00, b01, b02, b03, b10, b11, b12, b13;
    if (kq < 12) {
      const unsigned short* ga = gA + (kq + 1) * 64;
      va0 = *(const us8*)(ga);
      va1 = *(const us8*)(ga + 32 * 832);
      const unsigned short* g0 = gB + pl0[kq + 1] * PLANE;
      const unsigned short* g1p = gB + pl1[kq + 1] * PLANE;
      b00 = *(const us8*)(g0);        b01 = *(const us8*)(g0 + 2048);
      b02 = *(const us8*)(g0 + 4096); b03 = *(const us8*)(g0 + 6144);
      b10 = *(const us8*)(g1p);        b11 = *(const us8*)(g1p + 2048);
      b12 = *(const us8*)(g1p + 4096); b13 = *(const us8*)(g1p + 6144);
    }
    const unsigned short* Ab = &As[bf][nl * 64];
    const unsigned short* Bb = &Bs[bf][rsel][(nhh * 64 + nl) * 64];
    bf16x8 af[4][2], bfr[4][2];
    #pragma unroll
    for (int mt = 0; mt < 4; mt++) {
      af[mt][0] = *(const bf16x8*)(Ab + mt * 1024 + c0);
      af[mt][1] = *(const bf16x8*)(Ab + mt * 1024 + (c0 ^ 32));
    }
    #pragma unroll
    for (int nt = 0; nt < 4; nt++) {
      bfr[nt][0] = *(const bf16x8*)(Bb + nt * 1024 + c0);
      bfr[nt][1] = *(const bf16x8*)(Bb + nt * 1024 + (c0 ^ 32));
    }
    #pragma unroll
    for (int h = 0; h < 2; h++)
      #pragma unroll
      for (int mt = 0; mt < 4; mt++)
        #pragma unroll
        for (int nt = 0; nt < 4; nt++)
          acc[mt][nt] = MFMA(af[mt][h], bfr[nt][h], acc[mt][nt], 0, 0, 0);
    if (kq < 12) {
      unsigned short* la = lA + (bf ^ 1) * 4096;
      unsigned short* l0 = lB0 + (bf ^ 1) * 16384;
      unsigned short* l1 = lB1 + (bf ^ 1) * 16384;
      *(us8*)(la) = va0;  *(us8*)(la + 2048) = va1;
      *(us8*)(l0) = b00; *(us8*)(l0 + 2048) = b01;
      *(us8*)(l0 + 4096) = b02; *(us8*)(l0 + 6144) = b03;
      *(us8*)(l1) = b10; *(us8*)(l1 + 2048) = b11;
      *(us8*)(l1 + 4096) = b12; *(us8*)(l1 + 6144) = b13;
    }
    __syncthreads();
  }

  // epilogue: act2 -> z2T[r][b][o]
  const int rr = rA + rsel;
  #pragma unroll
  for (int mt = 0; mt < 4; mt++) {
    int ob = mt * 16 + quad * 4;
    f32x4 av = *(const f32x4*)(params + 256 + ob);
    f32x4 bv = *(const f32x4*)(params + 320 + ob);
    #pragma unroll
    for (int nt = 0; nt < 4; nt++) {
      int col = b0 + nhh * 64 + nt * 16 + nl;
      f32x4 a = acc[mt][nt];
      us4 w;
      w.x = f2bf(fmaxf(fmaf(a[0], av[0], bv[0]), 0.f));
      w.y = f2bf(fmaxf(fmaf(a[1], av[1], bv[1]), 0.f));
      w.z = f2bf(fmaxf(fmaf(a[2], av[2], bv[2]), 0.f));
      w.w = f2bf(fmaxf(fmaf(a[3], av[3], bv[3]), 0.f));
      *(us4*)(z2T + (rr * 2048 + col) * 64 + ob) = w;
    }
  }
}

// ---- gemm2: block = (btile=256 batches, r): C[128 x 256], 4 waves (2mh x 2nh),
//      wave tile 64 x 128 = 4m x 8n. BK=32, 52 K-steps, LDS 48 KB (2 blocks/CU).
//      Staging: global_load_lds 16B/lane, linear LDS dest; slab = 16 rows x 64 B.
//      Fragment reads: one ds_read_b128 per K=32 fragment, 64 B rows -> banks
//      naturally balanced (no swizzle).
__global__ __launch_bounds__(256, 2) void gemm2(const unsigned short* __restrict__ W23t,
                                                const unsigned short* __restrict__ z2T,
                                                const unsigned short* __restrict__ z3T,
                                                const int* __restrict__ nei,
                                                const float* __restrict__ params,
                                                unsigned short* __restrict__ outT) {
  __shared__ unsigned short As[2][4096];     // 128 rows x 32 shorts per buf (8 KB)
  __shared__ unsigned short Bs[2][8192];     // 256 rows x 32 shorts per buf (16 KB)

  const int bid = blockIdx.x;
  const int r = bid >> 3, btile = bid & 7;   // bid%8 = btile -> one btile per XCD
  const int b0 = btile << 8;
  const int t = threadIdx.x, wv = t >> 6, lane = t & 63;
  const int quad = lane >> 4, nl = lane & 15;
  const int mh = wv >> 1, nh = wv & 1;

  const int neibase = r * 13;

  // staging geometry: slab = 16 rows x 64 B = 1 KB = one gl16 per wave.
  // lane -> (slab-row lr = lane>>2, 16B-chunk lj = lane&3); linear, no swizzle.
  const int lr = lane >> 2, lj = lane & 3;
  // A: 8 slabs (128 rows); wave wv owns slabs 2wv, 2wv+1.
  int aoff[2];
  #pragma unroll
  for (int i = 0; i < 2; i++) aoff[i] = (16 * (2 * wv + i) + lr) * 3328 + lj * 16;
  // B: 16 slabs (256 rows); wave wv owns slabs 4wv..4wv+3.
  int boff[4];
  #pragma unroll
  for (int i = 0; i < 4; i++) boff[i] = (b0 + 16 * (4 * wv + i) + lr) * 128 + lj * 16;

  const char* gAb = (const char*)W23t;

  // stage step 0 (plane 0, half 0) into buffer 0
  {
    int p0 = nei[neibase];
    const char* gb = (const char*)(z2T + p0 * PLANE);
    #pragma unroll
    for (int i = 0; i < 2; i++)
      gl16(gAb + aoff[i], &As[0][(2 * wv + i) * 512]);
    #pragma unroll
    for (int i = 0; i < 4; i++)
      gl16(gb + boff[i], &Bs[0][(4 * wv + i) * 512]);
  }
  asm volatile("s_waitcnt vmcnt(0)" ::: "memory");
  __syncthreads();

  f32x4 acc[4][8] = {};
  #pragma unroll 1
  for (int s = 0; s < 52; s++) {
    const int buf = s & 1;
    if (s < 51) {
      const int kn = s + 1;
      const int pn = kn >> 1, hn = kn & 1;
      int p = nei[neibase + (pn < 13 ? pn : pn - 13)];
      const char* ga = gAb + pn * 128 + hn * 64;
      const char* gb = (const char*)((pn < 13 ? z2T : z3T) + p * PLANE) + hn * 64;
      #pragma unroll
      for (int i = 0; i < 2; i++)
        gl16(ga + aoff[i], &As[buf ^ 1][(2 * wv + i) * 512]);
      #pragma unroll
      for (int i = 0; i < 4; i++)
        gl16(gb + boff[i], &Bs[buf ^ 1][(4 * wv + i) * 512]);
    }
    const unsigned short* Ab = &As[buf][(mh * 64 + nl) * 32 + quad * 8];
    const unsigned short* Bb = &Bs[buf][(nh * 128 + nl) * 32 + quad * 8];
    bf16x8 af[4], bfr[8];
    #pragma unroll
    for (int mt = 0; mt < 4; mt++)
      af[mt] = *(const bf16x8*)(Ab + mt * 512);
    #pragma unroll
    for (int nt = 0; nt < 8; nt++)
      bfr[nt] = *(const bf16x8*)(Bb + nt * 512);
    #pragma unroll
    for (int mt = 0; mt < 4; mt++)
      #pragma unroll
      for (int nt = 0; nt < 8; nt++)
        acc[mt][nt] = MFMA(af[mt], bfr[nt], acc[mt][nt], 0, 0, 0);
    asm volatile("s_waitcnt vmcnt(0)" ::: "memory");
    __syncthreads();
  }

  // epilogue: + cc -> outT[r][b][o] bf16
  #pragma unroll
  for (int mt = 0; mt < 4; mt++) {
    int ob = mh * 64 + mt * 16 + quad * 4;
    f32x4 cv = *(const f32x4*)(params + 384 + ob);
    #pragma unroll
    for (int nt = 0; nt < 8; nt++) {
      int col = b0 + nh * 128 + nt * 16 + nl;
      f32x4 a = acc[mt][nt];
      us4 w;
      w.x = f2bf(a[0] + cv[0]);
      w.y = f2bf(a[1] + cv[1]);
      w.z = f2bf(a[2] + cv[2]);
      w.w = f2bf(a[3] + cv[3]);
      *(us4*)(outT + (r * 2048 + col) * 128 + ob) = w;
    }
  }
}

// ---- transpose-out: outT[r][b][o] bf16 -> out[b][o][r] f32
__global__ __launch_bounds__(256) void t_out(const unsigned short* __restrict__ outT,
                                             float* __restrict__ out) {
  __shared__ float ot[60 * 129];
  const int b = blockIdx.x, t = threadIdx.x;
  for (int i = t; i < 1920; i += 256) {
    int r = i >> 5, og = (i & 31) << 2;
    us4 v = *(const us4*)(outT + (r * 2048 + b) * 128 + og);
    ot[r * 129 + og + 0] = bf2f(v.x);
    ot[r * 129 + og + 1] = bf2f(v.y);
    ot[r * 129 + og + 2] = bf2f(v.z);
    ot[r * 129 + og + 3] = bf2f(v.w);
  }
  __syncthreads();
  int o = t >> 1, s = t & 1;
  float* dst = out + b * 7680 + o * 60 + s * 30;
  #pragma unroll
  for (int j = 0; j < 30; j++) dst[j] = ot[(s * 30 + j) * 129 + o];
}

extern "C" void kernel_launch(void* const* d_in, const int* in_sizes, int n_in,
                              void* d_out, int out_size, void* d_ws, size_t ws_size,
                              hipStream_t stream) {
  const float* x   = (const float*)d_in[0];
  const int*   nei = (const int*)d_in[1];
  const float* g1  = (const float*)d_in[2];
  const float* be1 = (const float*)d_in[3];
  const float* mu1 = (const float*)d_in[4];
  const float* va1 = (const float*)d_in[5];
  const float* W1  = (const float*)d_in[6];
  const float* c1  = (const float*)d_in[7];
  const float* g2  = (const float*)d_in[8];
  const float* be2 = (const float*)d_in[9];
  const float* mu2 = (const float*)d_in[10];
  const float* va2 = (const float*)d_in[11];
  const float* W2  = (const float*)d_in[12];
  const float* c2  = (const float*)d_in[13];
  const float* g3  = (const float*)d_in[14];
  const float* be3 = (const float*)d_in[15];
  const float* mu3 = (const float*)d_in[16];
  const float* va3 = (const float*)d_in[17];
  const float* W3  = (const float*)d_in[18];
  const float* c3  = (const float*)d_in[19];

  // ws layout (63.5 MB): W1t | W23t | params | z2T | z3T | big(z1T ∪ outT)
  unsigned short* W1t  = (unsigned short*)d_ws;
  unsigned short* W23t = W1t + 53248;
  float*          prm  = (float*)(W23t + 212992);
  unsigned short* z2T  = (unsigned short*)(prm + 512);
  unsigned short* z3T  = z2T + ZTOT;
  unsigned short* big  = z3T + ZTOT;       // z1T (read in gemm1) aliases outT (written in gemm2)
  unsigned short* z1T  = big;
  unsigned short* outT = big;

  prep_w<<<80, 256, 0, stream>>>(W1, W2, W3,
                                 g1, be1, mu1, va1, c1,
                                 g2, be2, mu2, va2, c2,
                                 g3, be3, mu3, va3, c3,
                                 W1t, W23t, prm);
  t_in<<<2048, 256, 0, stream>>>(x, prm, z1T, z3T);
  gemm1<<<480, 256, 0, stream>>>(W1t, z1T, nei, prm, z2T);
  gemm2<<<480, 256, 0, stream>>>(W23t, z2T, z3T, nei, prm, outT);
  t_out<<<2048, 256, 0, stream>>>(outT, (float*)d_out);
}

// Round 4
// 238.346 us; speedup vs baseline: 1.5647x; 1.0279x over previous
//
#include <hip/hip_runtime.h>
#include <hip/hip_bf16.h>

// Residual_Comb_Conv: B=2048, C_IN=64, C_MID=64, C_OUT=128, R=60, K=13
// R10: gemm2 = R9 geometry (128x256 block, 64x128 wave, BK=32, gl16 staging)
// with two fixes from R9's counters:
//  1. Proper XOR swizzle for 64 B rows (R9 had 4.79M bank-conflict cycles):
//     chunk_phys = j ^ ((row>>1)&3), applied on the pre-swizzled GLOBAL
//     source (LDS dest stays linear for gl16) and on the fragment-read
//     offset. 8 bank-groups x 8 lanes each -> conflict-free.
//  2. Triple-buffered counted-vmcnt pipeline (T3/T4): R9's per-step
//     vmcnt(0)+__syncthreads serialized LDS/MFMA/VMEM (sum 178k cyc/CU ==
//     measured 173k). Now: vmcnt(6) -> raw s_barrier -> sched_barrier ->
//     issue stage(s+2) -> compute(s). 2 stages in flight, no drain.
//     nei plane offsets precomputed in LDS (sOff) so the loop's only VMEM
//     ops are the 6 counted gl16s.

typedef __attribute__((ext_vector_type(8))) short bf16x8;
typedef __attribute__((ext_vector_type(4))) float f32x4;
typedef __attribute__((ext_vector_type(4))) unsigned short us4;
typedef __attribute__((ext_vector_type(8))) unsigned short us8;

#define EPSV 1e-5f
#define PLANE 131072           // 2048*64 shorts per z plane
#define ZTOT  7864320          // 60*PLANE

__device__ __forceinline__ unsigned short f2bf(float f) {
  unsigned int u = __builtin_bit_cast(unsigned int, f);
  u += 0x7FFFu + ((u >> 16) & 1u);   // round-to-nearest-even
  return (unsigned short)(u >> 16);
}
__device__ __forceinline__ float bf2f(unsigned short s) {
  unsigned int u = ((unsigned int)s) << 16;
  return __builtin_bit_cast(float, u);
}

// async global->LDS, 16B per lane, wave-uniform LDS base + lane*16 linear dest
typedef const __attribute__((address_space(1))) unsigned int gas_u32;
typedef __attribute__((address_space(3))) unsigned int las_u32;
__device__ __forceinline__ void gl16(const void* g, void* l) {
  __builtin_amdgcn_global_load_lds((gas_u32*)g, (las_u32*)l, 16, 0, 0);
}

// ---- prep: weights -> bf16 transposed layouts; last block also folds BN params
// params: [a1|b1|a3|b3|a2|b2p] (6*64) + cc (128) = 512 floats
__global__ void prep_w(const float* __restrict__ W1, const float* __restrict__ W2,
                       const float* __restrict__ W3,
                       const float* __restrict__ g1, const float* __restrict__ be1,
                       const float* __restrict__ mu1, const float* __restrict__ va1,
                       const float* __restrict__ c1,
                       const float* __restrict__ g2, const float* __restrict__ be2,
                       const float* __restrict__ mu2, const float* __restrict__ va2,
                       const float* __restrict__ c2,
                       const float* __restrict__ g3, const float* __restrict__ be3,
                       const float* __restrict__ mu3, const float* __restrict__ va3,
                       const float* __restrict__ c3,
                       unsigned short* __restrict__ W1t,
                       unsigned short* __restrict__ W23t,
                       float* __restrict__ params) {
  int t = blockIdx.x * 256 + threadIdx.x;
  if (t < 4096) {                        // W1: 64*64 (o,c) rows
    int o = t >> 6, c = t & 63;
    const float* src = W1 + (o * 64 + c) * 13;
    unsigned short* dst = W1t + o * 832 + c;
    #pragma unroll
    for (int ks = 0; ks < 13; ks++) dst[ks * 64] = f2bf(src[ks]);
  } else if (t < 20480) {                // W2,W3: 2*128*64 rows
    int idx = t - 4096;
    int half = idx >> 13;                // 0 -> W2, 1 -> W3
    int o = (idx >> 6) & 127, c = idx & 63;
    const float* src = (half ? W3 : W2) + (o * 64 + c) * 13;
    unsigned short* dst = W23t + o * 1664 + half * 13 * 64 + c;
    #pragma unroll
    for (int ks = 0; ks < 13; ks++) dst[ks * 64] = f2bf(src[ks]);
  }
  if (blockIdx.x == 79) {
    int u = threadIdx.x;
    if (u < 64) {
      float a1v = g1[u] * rsqrtf(va1[u] + EPSV);
      params[u]       = a1v;
      params[64 + u]  = be1[u] - mu1[u] * a1v;
      float a3v = g3[u] * rsqrtf(va3[u] + EPSV);
      params[128 + u] = a3v;
      params[192 + u] = be3[u] - mu3[u] * a3v;
      float a2v = g2[u] * rsqrtf(va2[u] + EPSV);
      params[256 + u] = a2v;
      params[320 + u] = be2[u] - mu2[u] * a2v + a2v * c1[u];  // fold conv1 bias
    }
    if (u < 128) params[384 + u] = c2[u] + c3[u];
  }
}

// ---- transpose-in: x[b][c][r] f32 -> z1T/z3T[r][b][c] bf16 with act1/act3
__global__ __launch_bounds__(256) void t_in(const float* __restrict__ x,
                                            const float* __restrict__ params,
                                            unsigned short* __restrict__ z1T,
                                            unsigned short* __restrict__ z3T) {
  __shared__ float xt[64 * 61];
  __shared__ float prm[256];
  const int b = blockIdx.x, t = threadIdx.x;
  prm[t] = params[t];                       // a1|b1|a3|b3
  for (int i = t; i < 3840; i += 256) {
    int c = i / 60;
    xt[c * 61 + (i - c * 60)] = x[b * 3840 + i];
  }
  __syncthreads();
  if (t < 240) {
    int r = t >> 2, g = t & 3, c0 = g << 4;
    us8 z1v0, z1v1, z3v0, z3v1;
    #pragma unroll
    for (int j = 0; j < 8; j++) {
      int c = c0 + j;
      float v = xt[c * 61 + r];
      z1v0[j] = f2bf(fmaxf(fmaf(v, prm[c], prm[64 + c]), 0.f));
      z3v0[j] = f2bf(fmaxf(fmaf(v, prm[128 + c], prm[192 + c]), 0.f));
    }
    #pragma unroll
    for (int j = 0; j < 8; j++) {
      int c = c0 + 8 + j;
      float v = xt[c * 61 + r];
      z1v1[j] = f2bf(fmaxf(fmaf(v, prm[c], prm[64 + c]), 0.f));
      z3v1[j] = f2bf(fmaxf(fmaf(v, prm[128 + c], prm[192 + c]), 0.f));
    }
    int idx = (r * 2048 + b) * 64 + c0;
    *(us8*)(z1T + idx) = z1v0;  *(us8*)(z1T + idx + 8) = z1v1;
    *(us8*)(z3T + idx) = z3v0;  *(us8*)(z3T + idx + 8) = z3v1;
  }
}

#define MFMA __builtin_amdgcn_mfma_f32_16x16x32_bf16

// ---- gemm1: block = (btile=128 batches, r-pair). C[64 x 128] for each of 2 r's.
//      A (W1t) staged once, shared. Waves: (rsel = w>>1, nhh = w&1); wave tile
//      64 rows x 64 cols = 4m x 4n of 16x16x32.
__global__ __launch_bounds__(256, 2) void gemm1(const unsigned short* __restrict__ W1t,
                                                const unsigned short* __restrict__ z1T,
                                                const int* __restrict__ nei,
                                                const float* __restrict__ params,
                                                unsigned short* __restrict__ z2T) {
  __shared__ unsigned short As[2][4096];        // 64 x 64 per buf
  __shared__ unsigned short Bs[2][2][8192];     // [buf][r] 128 x 64

  const int bid = blockIdx.x;
  const int rp = bid >> 4, btile = bid & 15;    // bid%8 = btile%8 -> XCD locality
  const int b0 = btile << 7;
  const int rA = rp * 2, rB = rA + 1;
  const int t = threadIdx.x, wave = t >> 6, lane = t & 63;
  const int quad = lane >> 4, nl = lane & 15;
  const int rsel = wave >> 1, nhh = wave & 1;

  int pl0[13], pl1[13];
  #pragma unroll
  for (int q = 0; q < 13; q++) { pl0[q] = nei[rA * 13 + q]; pl1[q] = nei[rB * 13 + q]; }

  const int trow = t >> 3, tj = t & 7;
  const int sw8 = ((tj ^ (trow & 7)) << 3);     // XOR-swizzled chunk (shorts)
  const unsigned short* gA = W1t + trow * 832 + tj * 8;
  const unsigned short* gB = z1T + (b0 + trow) * 64 + tj * 8;
  unsigned short* lA = &As[0][trow * 64 + sw8];
  unsigned short* lB0 = &Bs[0][0][trow * 64 + sw8];
  unsigned short* lB1 = &Bs[0][1][trow * 64 + sw8];

  // stage kq=0 into buffer 0
  {
    us8 va0 = *(const us8*)(gA);
    us8 va1 = *(const us8*)(gA + 32 * 832);
    const unsigned short* g0 = gB + pl0[0] * PLANE;
    const unsigned short* g1p = gB + pl1[0] * PLANE;
    us8 b00 = *(const us8*)(g0);
    us8 b01 = *(const us8*)(g0 + 2048);
    us8 b02 = *(const us8*)(g0 + 4096);
    us8 b03 = *(const us8*)(g0 + 6144);
    us8 b10 = *(const us8*)(g1p);
    us8 b11 = *(const us8*)(g1p + 2048);
    us8 b12 = *(const us8*)(g1p + 4096);
    us8 b13 = *(const us8*)(g1p + 6144);
    *(us8*)(lA) = va0;  *(us8*)(lA + 2048) = va1;
    *(us8*)(lB0) = b00; *(us8*)(lB0 + 2048) = b01;
    *(us8*)(lB0 + 4096) = b02; *(us8*)(lB0 + 6144) = b03;
    *(us8*)(lB1) = b10; *(us8*)(lB1 + 2048) = b11;
    *(us8*)(lB1 + 4096) = b12; *(us8*)(lB1 + 6144) = b13;
  }
  __syncthreads();

  const int c0 = ((quad ^ (nl & 7)) << 3);      // physical chunk for logical quad
  f32x4 acc[4][4] = {};
  #pragma unroll 1
  for (int kq = 0; kq < 13; kq++) {
    const int bf = kq & 1;
    us8 va0, va1, b00, b01, b02, b03, b10, b11, b12, b13;
    if (kq < 12) {
      const unsigned short* ga = gA + (kq + 1) * 64;
      va0 = *(const us8*)(ga);
      va1 = *(const us8*)(ga + 32 * 832);
      const unsigned short* g0 = gB + pl0[kq + 1] * PLANE;
      const unsigned short* g1p = gB + pl1[kq + 1] * PLANE;
      b00 = *(const us8*)(g0);        b01 = *(const us8*)(g0 + 2048);
      b02 = *(const us8*)(g0 + 4096); b03 = *(const us8*)(g0 + 6144);
      b10 = *(const us8*)(g1p);        b11 = *(const us8*)(g1p + 2048);
      b12 = *(const us8*)(g1p + 4096); b13 = *(const us8*)(g1p + 6144);
    }
    const unsigned short* Ab = &As[bf][nl * 64];
    const unsigned short* Bb = &Bs[bf][rsel][(nhh * 64 + nl) * 64];
    bf16x8 af[4][2], bfr[4][2];
    #pragma unroll
    for (int mt = 0; mt < 4; mt++) {
      af[mt][0] = *(const bf16x8*)(Ab + mt * 1024 + c0);
      af[mt][1] = *(const bf16x8*)(Ab + mt * 1024 + (c0 ^ 32));
    }
    #pragma unroll
    for (int nt = 0; nt < 4; nt++) {
      bfr[nt][0] = *(const bf16x8*)(Bb + nt * 1024 + c0);
      bfr[nt][1] = *(const bf16x8*)(Bb + nt * 1024 + (c0 ^ 32));
    }
    #pragma unroll
    for (int h = 0; h < 2; h++)
      #pragma unroll
      for (int mt = 0; mt < 4; mt++)
        #pragma unroll
        for (int nt = 0; nt < 4; nt++)
          acc[mt][nt] = MFMA(af[mt][h], bfr[nt][h], acc[mt][nt], 0, 0, 0);
    if (kq < 12) {
      unsigned short* la = lA + (bf ^ 1) * 4096;
      unsigned short* l0 = lB0 + (bf ^ 1) * 16384;
      unsigned short* l1 = lB1 + (bf ^ 1) * 16384;
      *(us8*)(la) = va0;  *(us8*)(la + 2048) = va1;
      *(us8*)(l0) = b00; *(us8*)(l0 + 2048) = b01;
      *(us8*)(l0 + 4096) = b02; *(us8*)(l0 + 6144) = b03;
      *(us8*)(l1) = b10; *(us8*)(l1 + 2048) = b11;
      *(us8*)(l1 + 4096) = b12; *(us8*)(l1 + 6144) = b13;
    }
    __syncthreads();
  }

  // epilogue: act2 -> z2T[r][b][o]
  const int rr = rA + rsel;
  #pragma unroll
  for (int mt = 0; mt < 4; mt++) {
    int ob = mt * 16 + quad * 4;
    f32x4 av = *(const f32x4*)(params + 256 + ob);
    f32x4 bv = *(const f32x4*)(params + 320 + ob);
    #pragma unroll
    for (int nt = 0; nt < 4; nt++) {
      int col = b0 + nhh * 64 + nt * 16 + nl;
      f32x4 a = acc[mt][nt];
      us4 w;
      w.x = f2bf(fmaxf(fmaf(a[0], av[0], bv[0]), 0.f));
      w.y = f2bf(fmaxf(fmaf(a[1], av[1], bv[1]), 0.f));
      w.z = f2bf(fmaxf(fmaf(a[2], av[2], bv[2]), 0.f));
      w.w = f2bf(fmaxf(fmaf(a[3], av[3], bv[3]), 0.f));
      *(us4*)(z2T + (rr * 2048 + col) * 64 + ob) = w;
    }
  }
}

// ---- gemm2: block = (btile=256 batches, r): C[128 x 256], 4 waves (2mh x 2nh),
//      wave tile 64 x 128 = 4m x 8n. BK=32, 52 K-steps.
//      Triple-buffered (72 KB, 2 blocks/CU), counted vmcnt(6) + raw s_barrier:
//      2 stages in flight, no drain in the main loop.
//      Swizzle: LDS[row][chunk j] holds global chunk j ^ ((row>>1)&3); applied
//      on the global source (linear gl16 dest) and on fragment reads.
__global__ __launch_bounds__(256, 2) void gemm2(const unsigned short* __restrict__ W23t,
                                                const unsigned short* __restrict__ z2T,
                                                const unsigned short* __restrict__ z3T,
                                                const int* __restrict__ nei,
                                                const float* __restrict__ params,
                                                unsigned short* __restrict__ outT) {
  __shared__ unsigned short As[3][4096];     // 128 rows x 32 shorts per buf (8 KB)
  __shared__ unsigned short Bs[3][8192];     // 256 rows x 32 shorts per buf (16 KB)
  __shared__ int sOff[26];                   // per-plane byte offsets from z2T

  const int bid = blockIdx.x;
  const int r = bid >> 3, btile = bid & 7;   // bid%8 = btile -> one btile per XCD
  const int b0 = btile << 8;
  const int t = threadIdx.x, wv = t >> 6, lane = t & 63;
  const int quad = lane >> 4, nl = lane & 15;
  const int mh = wv >> 1, nh = wv & 1;

  if (t < 26) {
    int idx = t < 13 ? t : t - 13;
    int p = nei[r * 13 + idx];
    sOff[t] = p * (PLANE * 2) + (t < 13 ? 0 : ZTOT * 2);
  }

  // staging geometry: slab = 16 rows x 64 B = 1 KB = one gl16 per wave.
  // lane -> (slab-row lr = lane>>2, chunk lj = lane&3); source chunk
  // pre-swizzled lj ^ ((lr>>1)&3) so the (linear-dest) LDS ends up swizzled.
  const int lr = lane >> 2, lj = lane & 3;
  const int sj = ((lj ^ ((lr >> 1) & 3)) << 4);   // byte offset in source row
  // A: 8 slabs (128 rows); wave wv owns slabs 2wv, 2wv+1.
  int aoff[2];
  #pragma unroll
  for (int i = 0; i < 2; i++) aoff[i] = (16 * (2 * wv + i) + lr) * 3328 + sj;
  // B: 16 slabs (256 rows); wave wv owns slabs 4wv..4wv+3.
  int boff[4];
  #pragma unroll
  for (int i = 0; i < 4; i++) boff[i] = (b0 + 16 * (4 * wv + i) + lr) * 128 + sj;

  const char* gAb = (const char*)W23t;
  const char* z2b = (const char*)z2T;

  __syncthreads();                           // sOff visible

  // prologue: stage kn=0 -> buf0, kn=1 -> buf1 (plane 0, halves 0/1)
  {
    const char* gb = z2b + sOff[0];
    #pragma unroll
    for (int i = 0; i < 2; i++) gl16(gAb + aoff[i], &As[0][(2 * wv + i) * 512]);
    #pragma unroll
    for (int i = 0; i < 4; i++) gl16(gb + boff[i], &Bs[0][(4 * wv + i) * 512]);
    #pragma unroll
    for (int i = 0; i < 2; i++) gl16(gAb + 64 + aoff[i], &As[1][(2 * wv + i) * 512]);
    #pragma unroll
    for (int i = 0; i < 4; i++) gl16(gb + 64 + boff[i], &Bs[1][(4 * wv + i) * 512]);
  }

  const int rc = ((quad ^ ((nl >> 1) & 3)) << 3);  // read-side swizzled chunk (shorts)
  const int aro = (mh * 64 + nl) * 32 + rc;
  const int bro = (nh * 128 + nl) * 32 + rc;

  f32x4 acc[4][8] = {};
  int cb = 0, sb = 2;                        // compute buf = s%3, stage buf = (s+2)%3
  #pragma unroll 1
  for (int s = 0; s < 51; s++) {
    asm volatile("s_waitcnt vmcnt(6)" ::: "memory");   // own stage(s) landed
    __builtin_amdgcn_s_barrier();                      // everyone's stage(s) landed,
    __builtin_amdgcn_sched_barrier(0);                 // prev reads consumed
    const int kn = s + 2;
    if (kn < 52) {                           // stage kn into buf sb
      const int pn = kn >> 1;
      int off = sOff[pn] + ((kn & 1) << 6);
      const char* ga = gAb + kn * 64;
      const char* gb = z2b + off;
      #pragma unroll
      for (int i = 0; i < 2; i++) gl16(ga + aoff[i], &As[sb][(2 * wv + i) * 512]);
      #pragma unroll
      for (int i = 0; i < 4; i++) gl16(gb + boff[i], &Bs[sb][(4 * wv + i) * 512]);
    }
    const unsigned short* Ab = &As[cb][aro];
    const unsigned short* Bb = &Bs[cb][bro];
    bf16x8 af[4], bfr[8];
    #pragma unroll
    for (int mt = 0; mt < 4; mt++)
      af[mt] = *(const bf16x8*)(Ab + mt * 512);
    #pragma unroll
    for (int nt = 0; nt < 8; nt++)
      bfr[nt] = *(const bf16x8*)(Bb + nt * 512);
    #pragma unroll
    for (int mt = 0; mt < 4; mt++)
      #pragma unroll
      for (int nt = 0; nt < 8; nt++)
        acc[mt][nt] = MFMA(af[mt], bfr[nt], acc[mt][nt], 0, 0, 0);
    cb = (cb == 2) ? 0 : cb + 1;
    sb = (sb == 2) ? 0 : sb + 1;
  }
  // peeled last step (s=51, cb=0)
  {
    asm volatile("s_waitcnt vmcnt(0)" ::: "memory");
    __builtin_amdgcn_s_barrier();
    __builtin_amdgcn_sched_barrier(0);
    const unsigned short* Ab = &As[0][aro];
    const unsigned short* Bb = &Bs[0][bro];
    bf16x8 af[4], bfr[8];
    #pragma unroll
    for (int mt = 0; mt < 4; mt++)
      af[mt] = *(const bf16x8*)(Ab + mt * 512);
    #pragma unroll
    for (int nt = 0; nt < 8; nt++)
      bfr[nt] = *(const bf16x8*)(Bb + nt * 512);
    #pragma unroll
    for (int mt = 0; mt < 4; mt++)
      #pragma unroll
      for (int nt = 0; nt < 8; nt++)
        acc[mt][nt] = MFMA(af[mt], bfr[nt], acc[mt][nt], 0, 0, 0);
  }

  // epilogue: + cc -> outT[r][b][o] bf16
  #pragma unroll
  for (int mt = 0; mt < 4; mt++) {
    int ob = mh * 64 + mt * 16 + quad * 4;
    f32x4 cv = *(const f32x4*)(params + 384 + ob);
    #pragma unroll
    for (int nt = 0; nt < 8; nt++) {
      int col = b0 + nh * 128 + nt * 16 + nl;
      f32x4 a = acc[mt][nt];
      us4 w;
      w.x = f2bf(a[0] + cv[0]);
      w.y = f2bf(a[1] + cv[1]);
      w.z = f2bf(a[2] + cv[2]);
      w.w = f2bf(a[3] + cv[3]);
      *(us4*)(outT + (r * 2048 + col) * 128 + ob) = w;
    }
  }
}

// ---- transpose-out: outT[r][b][o] bf16 -> out[b][o][r] f32
__global__ __launch_bounds__(256) void t_out(const unsigned short* __restrict__ outT,
                                             float* __restrict__ out) {
  __shared__ float ot[60 * 129];
  const int b = blockIdx.x, t = threadIdx.x;
  for (int i = t; i < 1920; i += 256) {
    int r = i >> 5, og = (i & 31) << 2;
    us4 v = *(const us4*)(outT + (r * 2048 + b) * 128 + og);
    ot[r * 129 + og + 0] = bf2f(v.x);
    ot[r * 129 + og + 1] = bf2f(v.y);
    ot[r * 129 + og + 2] = bf2f(v.z);
    ot[r * 129 + og + 3] = bf2f(v.w);
  }
  __syncthreads();
  int o = t >> 1, s = t & 1;
  float* dst = out + b * 7680 + o * 60 + s * 30;
  #pragma unroll
  for (int j = 0; j < 30; j++) dst[j] = ot[(s * 30 + j) * 129 + o];
}

extern "C" void kernel_launch(void* const* d_in, const int* in_sizes, int n_in,
                              void* d_out, int out_size, void* d_ws, size_t ws_size,
                              hipStream_t stream) {
  const float* x   = (const float*)d_in[0];
  const int*   nei = (const int*)d_in[1];
  const float* g1  = (const float*)d_in[2];
  const float* be1 = (const float*)d_in[3];
  const float* mu1 = (const float*)d_in[4];
  const float* va1 = (const float*)d_in[5];
  const float* W1  = (const float*)d_in[6];
  const float* c1  = (const float*)d_in[7];
  const float* g2  = (const float*)d_in[8];
  const float* be2 = (const float*)d_in[9];
  const float* mu2 = (const float*)d_in[10];
  const float* va2 = (const float*)d_in[11];
  const float* W2  = (const float*)d_in[12];
  const float* c2  = (const float*)d_in[13];
  const float* g3  = (const float*)d_in[14];
  const float* be3 = (const float*)d_in[15];
  const float* mu3 = (const float*)d_in[16];
  const float* va3 = (const float*)d_in[17];
  const float* W3  = (const float*)d_in[18];
  const float* c3  = (const float*)d_in[19];

  // ws layout (63.5 MB): W1t | W23t | params | z2T | z3T | big(z1T ∪ outT)
  unsigned short* W1t  = (unsigned short*)d_ws;
  unsigned short* W23t = W1t + 53248;
  float*          prm  = (float*)(W23t + 212992);
  unsigned short* z2T  = (unsigned short*)(prm + 512);
  unsigned short* z3T  = z2T + ZTOT;
  unsigned short* big  = z3T + ZTOT;       // z1T (read in gemm1) aliases outT (written in gemm2)
  unsigned short* z1T  = big;
  unsigned short* outT = big;

  prep_w<<<80, 256, 0, stream>>>(W1, W2, W3,
                                 g1, be1, mu1, va1, c1,
                                 g2, be2, mu2, va2, c2,
                                 g3, be3, mu3, va3, c3,
                                 W1t, W23t, prm);
  t_in<<<2048, 256, 0, stream>>>(x, prm, z1T, z3T);
  gemm1<<<480, 256, 0, stream>>>(W1t, z1T, nei, prm, z2T);
  gemm2<<<480, 256, 0, stream>>>(W23t, z2T, z3T, nei, prm, outT);
  t_out<<<2048, 256, 0, stream>>>(outT, (float*)d_out);
}

// Round 5
// 235.383 us; speedup vs baseline: 1.5844x; 1.0126x over previous
//
#include <hip/hip_runtime.h>
#include <hip/hip_bf16.h>

// Residual_Comb_Conv: B=2048, C_IN=64, C_MID=64, C_OUT=128, R=60, K=13
// R11: gemm2 = R10 geometry (128x256 block, 64x128 wave, BK=32, triple-buffer,
// verified conflict-free source-side swizzle) + the m201 two-barrier phase
// discipline that R10 lacked (R10 was the m196 "coarse split that HURTS"):
//   per step: {ds_read cur || issue stage(s+2)} -> b1 -> lgkmcnt(0) ->
//             sched_barrier -> setprio(1) -> 32 MFMA -> setprio(0) ->
//             sched_barrier -> vmcnt(6) -> b2
//   - vmcnt(6) sits BEFORE b2 so every wave certifies stage(s+1) before any
//     wave reads it next step (counted, never drained in-loop).
//   - two co-resident blocks run phase-shifted; setprio favors the MFMA-
//     phase block (T5 requires this role split; null without it).

typedef __attribute__((ext_vector_type(8))) short bf16x8;
typedef __attribute__((ext_vector_type(4))) float f32x4;
typedef __attribute__((ext_vector_type(4))) unsigned short us4;
typedef __attribute__((ext_vector_type(8))) unsigned short us8;

#define EPSV 1e-5f
#define PLANE 131072           // 2048*64 shorts per z plane
#define ZTOT  7864320          // 60*PLANE

__device__ __forceinline__ unsigned short f2bf(float f) {
  unsigned int u = __builtin_bit_cast(unsigned int, f);
  u += 0x7FFFu + ((u >> 16) & 1u);   // round-to-nearest-even
  return (unsigned short)(u >> 16);
}
__device__ __forceinline__ float bf2f(unsigned short s) {
  unsigned int u = ((unsigned int)s) << 16;
  return __builtin_bit_cast(float, u);
}

// async global->LDS, 16B per lane, wave-uniform LDS base + lane*16 linear dest
typedef const __attribute__((address_space(1))) unsigned int gas_u32;
typedef __attribute__((address_space(3))) unsigned int las_u32;
__device__ __forceinline__ void gl16(const void* g, void* l) {
  __builtin_amdgcn_global_load_lds((gas_u32*)g, (las_u32*)l, 16, 0, 0);
}

// ---- prep: weights -> bf16 transposed layouts; last block also folds BN params
// params: [a1|b1|a3|b3|a2|b2p] (6*64) + cc (128) = 512 floats
__global__ void prep_w(const float* __restrict__ W1, const float* __restrict__ W2,
                       const float* __restrict__ W3,
                       const float* __restrict__ g1, const float* __restrict__ be1,
                       const float* __restrict__ mu1, const float* __restrict__ va1,
                       const float* __restrict__ c1,
                       const float* __restrict__ g2, const float* __restrict__ be2,
                       const float* __restrict__ mu2, const float* __restrict__ va2,
                       const float* __restrict__ c2,
                       const float* __restrict__ g3, const float* __restrict__ be3,
                       const float* __restrict__ mu3, const float* __restrict__ va3,
                       const float* __restrict__ c3,
                       unsigned short* __restrict__ W1t,
                       unsigned short* __restrict__ W23t,
                       float* __restrict__ params) {
  int t = blockIdx.x * 256 + threadIdx.x;
  if (t < 4096) {                        // W1: 64*64 (o,c) rows
    int o = t >> 6, c = t & 63;
    const float* src = W1 + (o * 64 + c) * 13;
    unsigned short* dst = W1t + o * 832 + c;
    #pragma unroll
    for (int ks = 0; ks < 13; ks++) dst[ks * 64] = f2bf(src[ks]);
  } else if (t < 20480) {                // W2,W3: 2*128*64 rows
    int idx = t - 4096;
    int half = idx >> 13;                // 0 -> W2, 1 -> W3
    int o = (idx >> 6) & 127, c = idx & 63;
    const float* src = (half ? W3 : W2) + (o * 64 + c) * 13;
    unsigned short* dst = W23t + o * 1664 + half * 13 * 64 + c;
    #pragma unroll
    for (int ks = 0; ks < 13; ks++) dst[ks * 64] = f2bf(src[ks]);
  }
  if (blockIdx.x == 79) {
    int u = threadIdx.x;
    if (u < 64) {
      float a1v = g1[u] * rsqrtf(va1[u] + EPSV);
      params[u]       = a1v;
      params[64 + u]  = be1[u] - mu1[u] * a1v;
      float a3v = g3[u] * rsqrtf(va3[u] + EPSV);
      params[128 + u] = a3v;
      params[192 + u] = be3[u] - mu3[u] * a3v;
      float a2v = g2[u] * rsqrtf(va2[u] + EPSV);
      params[256 + u] = a2v;
      params[320 + u] = be2[u] - mu2[u] * a2v + a2v * c1[u];  // fold conv1 bias
    }
    if (u < 128) params[384 + u] = c2[u] + c3[u];
  }
}

// ---- transpose-in: x[b][c][r] f32 -> z1T/z3T[r][b][c] bf16 with act1/act3
__global__ __launch_bounds__(256) void t_in(const float* __restrict__ x,
                                            const float* __restrict__ params,
                                            unsigned short* __restrict__ z1T,
                                            unsigned short* __restrict__ z3T) {
  __shared__ float xt[64 * 61];
  __shared__ float prm[256];
  const int b = blockIdx.x, t = threadIdx.x;
  prm[t] = params[t];                       // a1|b1|a3|b3
  for (int i = t; i < 3840; i += 256) {
    int c = i / 60;
    xt[c * 61 + (i - c * 60)] = x[b * 3840 + i];
  }
  __syncthreads();
  if (t < 240) {
    int r = t >> 2, g = t & 3, c0 = g << 4;
    us8 z1v0, z1v1, z3v0, z3v1;
    #pragma unroll
    for (int j = 0; j < 8; j++) {
      int c = c0 + j;
      float v = xt[c * 61 + r];
      z1v0[j] = f2bf(fmaxf(fmaf(v, prm[c], prm[64 + c]), 0.f));
      z3v0[j] = f2bf(fmaxf(fmaf(v, prm[128 + c], prm[192 + c]), 0.f));
    }
    #pragma unroll
    for (int j = 0; j < 8; j++) {
      int c = c0 + 8 + j;
      float v = xt[c * 61 + r];
      z1v1[j] = f2bf(fmaxf(fmaf(v, prm[c], prm[64 + c]), 0.f));
      z3v1[j] = f2bf(fmaxf(fmaf(v, prm[128 + c], prm[192 + c]), 0.f));
    }
    int idx = (r * 2048 + b) * 64 + c0;
    *(us8*)(z1T + idx) = z1v0;  *(us8*)(z1T + idx + 8) = z1v1;
    *(us8*)(z3T + idx) = z3v0;  *(us8*)(z3T + idx + 8) = z3v1;
  }
}

#define MFMA __builtin_amdgcn_mfma_f32_16x16x32_bf16

// ---- gemm1: block = (btile=128 batches, r-pair). C[64 x 128] for each of 2 r's.
//      A (W1t) staged once, shared. Waves: (rsel = w>>1, nhh = w&1); wave tile
//      64 rows x 64 cols = 4m x 4n of 16x16x32.
__global__ __launch_bounds__(256, 2) void gemm1(const unsigned short* __restrict__ W1t,
                                                const unsigned short* __restrict__ z1T,
                                                const int* __restrict__ nei,
                                                const float* __restrict__ params,
                                                unsigned short* __restrict__ z2T) {
  __shared__ unsigned short As[2][4096];        // 64 x 64 per buf
  __shared__ unsigned short Bs[2][2][8192];     // [buf][r] 128 x 64

  const int bid = blockIdx.x;
  const int rp = bid >> 4, btile = bid & 15;    // bid%8 = btile%8 -> XCD locality
  const int b0 = btile << 7;
  const int rA = rp * 2, rB = rA + 1;
  const int t = threadIdx.x, wave = t >> 6, lane = t & 63;
  const int quad = lane >> 4, nl = lane & 15;
  const int rsel = wave >> 1, nhh = wave & 1;

  int pl0[13], pl1[13];
  #pragma unroll
  for (int q = 0; q < 13; q++) { pl0[q] = nei[rA * 13 + q]; pl1[q] = nei[rB * 13 + q]; }

  const int trow = t >> 3, tj = t & 7;
  const int sw8 = ((tj ^ (trow & 7)) << 3);     // XOR-swizzled chunk (shorts)
  const unsigned short* gA = W1t + trow * 832 + tj * 8;
  const unsigned short* gB = z1T + (b0 + trow) * 64 + tj * 8;
  unsigned short* lA = &As[0][trow * 64 + sw8];
  unsigned short* lB0 = &Bs[0][0][trow * 64 + sw8];
  unsigned short* lB1 = &Bs[0][1][trow * 64 + sw8];

  // stage kq=0 into buffer 0
  {
    us8 va0 = *(const us8*)(gA);
    us8 va1 = *(const us8*)(gA + 32 * 832);
    const unsigned short* g0 = gB + pl0[0] * PLANE;
    const unsigned short* g1p = gB + pl1[0] * PLANE;
    us8 b00 = *(const us8*)(g0);
    us8 b01 = *(const us8*)(g0 + 2048);
    us8 b02 = *(const us8*)(g0 + 4096);
    us8 b03 = *(const us8*)(g0 + 6144);
    us8 b10 = *(const us8*)(g1p);
    us8 b11 = *(const us8*)(g1p + 2048);
    us8 b12 = *(const us8*)(g1p + 4096);
    us8 b13 = *(const us8*)(g1p + 6144);
    *(us8*)(lA) = va0;  *(us8*)(lA + 2048) = va1;
    *(us8*)(lB0) = b00; *(us8*)(lB0 + 2048) = b01;
    *(us8*)(lB0 + 4096) = b02; *(us8*)(lB0 + 6144) = b03;
    *(us8*)(lB1) = b10; *(us8*)(lB1 + 2048) = b11;
    *(us8*)(lB1 + 4096) = b12; *(us8*)(lB1 + 6144) = b13;
  }
  __syncthreads();

  const int c0 = ((quad ^ (nl & 7)) << 3);      // physical chunk for logical quad
  f32x4 acc[4][4] = {};
  #pragma unroll 1
  for (int kq = 0; kq < 13; kq++) {
    const int bf = kq & 1;
    us8 va0, va1, b00, b01, b02, b03, b10, b11, b12, b13;
    if (kq < 12) {
      const unsigned short* ga = gA + (kq + 1) * 64;
      va0 = *(const us8*)(ga);
      va1 = *(const us8*)(ga + 32 * 832);
      const unsigned short* g0 = gB + pl0[kq + 1] * PLANE;
      const unsigned short* g1p = gB + pl1[kq + 1] * PLANE;
      b00 = *(const us8*)(g0);        b01 = *(const us8*)(g0 + 2048);
      b02 = *(const us8*)(g0 + 4096); b03 = *(const us8*)(g0 + 6144);
      b10 = *(const us8*)(g1p);        b11 = *(const us8*)(g1p + 2048);
      b12 = *(const us8*)(g1p + 4096); b13 = *(const us8*)(g1p + 6144);
    }
    const unsigned short* Ab = &As[bf][nl * 64];
    const unsigned short* Bb = &Bs[bf][rsel][(nhh * 64 + nl) * 64];
    bf16x8 af[4][2], bfr[4][2];
    #pragma unroll
    for (int mt = 0; mt < 4; mt++) {
      af[mt][0] = *(const bf16x8*)(Ab + mt * 1024 + c0);
      af[mt][1] = *(const bf16x8*)(Ab + mt * 1024 + (c0 ^ 32));
    }
    #pragma unroll
    for (int nt = 0; nt < 4; nt++) {
      bfr[nt][0] = *(const bf16x8*)(Bb + nt * 1024 + c0);
      bfr[nt][1] = *(const bf16x8*)(Bb + nt * 1024 + (c0 ^ 32));
    }
    #pragma unroll
    for (int h = 0; h < 2; h++)
      #pragma unroll
      for (int mt = 0; mt < 4; mt++)
        #pragma unroll
        for (int nt = 0; nt < 4; nt++)
          acc[mt][nt] = MFMA(af[mt][h], bfr[nt][h], acc[mt][nt], 0, 0, 0);
    if (kq < 12) {
      unsigned short* la = lA + (bf ^ 1) * 4096;
      unsigned short* l0 = lB0 + (bf ^ 1) * 16384;
      unsigned short* l1 = lB1 + (bf ^ 1) * 16384;
      *(us8*)(la) = va0;  *(us8*)(la + 2048) = va1;
      *(us8*)(l0) = b00; *(us8*)(l0 + 2048) = b01;
      *(us8*)(l0 + 4096) = b02; *(us8*)(l0 + 6144) = b03;
      *(us8*)(l1) = b10; *(us8*)(l1 + 2048) = b11;
      *(us8*)(l1 + 4096) = b12; *(us8*)(l1 + 6144) = b13;
    }
    __syncthreads();
  }

  // epilogue: act2 -> z2T[r][b][o]
  const int rr = rA + rsel;
  #pragma unroll
  for (int mt = 0; mt < 4; mt++) {
    int ob = mt * 16 + quad * 4;
    f32x4 av = *(const f32x4*)(params + 256 + ob);
    f32x4 bv = *(const f32x4*)(params + 320 + ob);
    #pragma unroll
    for (int nt = 0; nt < 4; nt++) {
      int col = b0 + nhh * 64 + nt * 16 + nl;
      f32x4 a = acc[mt][nt];
      us4 w;
      w.x = f2bf(fmaxf(fmaf(a[0], av[0], bv[0]), 0.f));
      w.y = f2bf(fmaxf(fmaf(a[1], av[1], bv[1]), 0.f));
      w.z = f2bf(fmaxf(fmaf(a[2], av[2], bv[2]), 0.f));
      w.w = f2bf(fmaxf(fmaf(a[3], av[3], bv[3]), 0.f));
      *(us4*)(z2T + (rr * 2048 + col) * 64 + ob) = w;
    }
  }
}

// ---- gemm2: block = (btile=256 batches, r): C[128 x 256], 4 waves (2mh x 2nh),
//      wave tile 64 x 128 = 4m x 8n. BK=32, 52 K-steps, triple-buffered.
//      m201-style phases: {ds_read cur || stage s+2} b1 lgkm(0) setprio MFMA
//      setprio(0) vmcnt(6) b2. Counted vmcnt before b2 certifies stage(s+1)
//      block-wide before anyone reads it.
__global__ __launch_bounds__(256, 2) void gemm2(const unsigned short* __restrict__ W23t,
                                                const unsigned short* __restrict__ z2T,
                                                const unsigned short* __restrict__ z3T,
                                                const int* __restrict__ nei,
                                                const float* __restrict__ params,
                                                unsigned short* __restrict__ outT) {
  __shared__ unsigned short As[3][4096];     // 128 rows x 32 shorts per buf (8 KB)
  __shared__ unsigned short Bs[3][8192];     // 256 rows x 32 shorts per buf (16 KB)
  __shared__ int sOff[26];                   // per-plane byte offsets from z2T

  const int bid = blockIdx.x;
  const int r = bid >> 3, btile = bid & 7;   // bid%8 = btile -> one btile per XCD
  const int b0 = btile << 8;
  const int t = threadIdx.x, wv = t >> 6, lane = t & 63;
  const int quad = lane >> 4, nl = lane & 15;
  const int mh = wv >> 1, nh = wv & 1;

  if (t < 26) {
    int idx = t < 13 ? t : t - 13;
    int p = nei[r * 13 + idx];
    sOff[t] = p * (PLANE * 2) + (t < 13 ? 0 : ZTOT * 2);
  }

  // staging geometry: slab = 16 rows x 64 B = 1 KB = one gl16 per wave.
  // lane -> (slab-row lr = lane>>2, chunk lj = lane&3); source chunk
  // pre-swizzled lj ^ ((lr>>1)&3) so the (linear-dest) LDS ends up swizzled.
  const int lr = lane >> 2, lj = lane & 3;
  const int sj = ((lj ^ ((lr >> 1) & 3)) << 4);   // byte offset in source row
  // A: 8 slabs (128 rows); wave wv owns slabs 2wv, 2wv+1.
  int aoff[2];
  #pragma unroll
  for (int i = 0; i < 2; i++) aoff[i] = (16 * (2 * wv + i) + lr) * 3328 + sj;
  // B: 16 slabs (256 rows); wave wv owns slabs 4wv..4wv+3.
  int boff[4];
  #pragma unroll
  for (int i = 0; i < 4; i++) boff[i] = (b0 + 16 * (4 * wv + i) + lr) * 128 + sj;

  const char* gAb = (const char*)W23t;
  const char* z2b = (const char*)z2T;

  __syncthreads();                           // sOff visible

  // prologue: stage kn=0 -> buf0, kn=1 -> buf1 (plane 0, halves 0/1)
  {
    const char* gb = z2b + sOff[0];
    #pragma unroll
    for (int i = 0; i < 2; i++) gl16(gAb + aoff[i], &As[0][(2 * wv + i) * 512]);
    #pragma unroll
    for (int i = 0; i < 4; i++) gl16(gb + boff[i], &Bs[0][(4 * wv + i) * 512]);
    #pragma unroll
    for (int i = 0; i < 2; i++) gl16(gAb + 64 + aoff[i], &As[1][(2 * wv + i) * 512]);
    #pragma unroll
    for (int i = 0; i < 4; i++) gl16(gb + 64 + boff[i], &Bs[1][(4 * wv + i) * 512]);
  }
  asm volatile("s_waitcnt vmcnt(6)" ::: "memory");   // own stage-0 landed
  __builtin_amdgcn_s_barrier();                      // everyone's stage-0 landed

  const int rc = ((quad ^ ((nl >> 1) & 3)) << 3);  // read-side swizzled chunk (shorts)
  const int aro = (mh * 64 + nl) * 32 + rc;
  const int bro = (nh * 128 + nl) * 32 + rc;

  f32x4 acc[4][8] = {};
  int cb = 0, sb = 2;                        // compute buf = s%3, stage buf = (s+2)%3
  #pragma unroll 1
  for (int s = 0; s < 51; s++) {
    // R1: ds_read current buf + issue stage(s+2)
    const unsigned short* Ab = &As[cb][aro];
    const unsigned short* Bb = &Bs[cb][bro];
    bf16x8 af[4], bfr[8];
    #pragma unroll
    for (int mt = 0; mt < 4; mt++)
      af[mt] = *(const bf16x8*)(Ab + mt * 512);
    #pragma unroll
    for (int nt = 0; nt < 8; nt++)
      bfr[nt] = *(const bf16x8*)(Bb + nt * 512);
    const int kn = s + 2;
    if (kn < 52) {
      const int pn = kn >> 1;
      int off = sOff[pn] + ((kn & 1) << 6);
      const char* ga = gAb + kn * 64;
      const char* gb = z2b + off;
      #pragma unroll
      for (int i = 0; i < 2; i++) gl16(ga + aoff[i], &As[sb][(2 * wv + i) * 512]);
      #pragma unroll
      for (int i = 0; i < 4; i++) gl16(gb + boff[i], &Bs[sb][(4 * wv + i) * 512]);
    }
    __builtin_amdgcn_s_barrier();                      // b1: all reads issued
    asm volatile("s_waitcnt lgkmcnt(0)" ::: "memory"); // frags in registers
    __builtin_amdgcn_sched_barrier(0);
    __builtin_amdgcn_s_setprio(1);
    #pragma unroll
    for (int mt = 0; mt < 4; mt++)
      #pragma unroll
      for (int nt = 0; nt < 8; nt++)
        acc[mt][nt] = MFMA(af[mt], bfr[nt], acc[mt][nt], 0, 0, 0);
    __builtin_amdgcn_s_setprio(0);
    __builtin_amdgcn_sched_barrier(0);
    asm volatile("s_waitcnt vmcnt(6)" ::: "memory");   // stage(s+1) landed (own)
    __builtin_amdgcn_s_barrier();                      // b2: landed block-wide
    cb = (cb == 2) ? 0 : cb + 1;
    sb = (sb == 2) ? 0 : sb + 1;
  }
  // peeled last step (s=51, cb=0): stage-51 certified via vmcnt(0)+barrier
  {
    asm volatile("s_waitcnt vmcnt(0)" ::: "memory");
    __builtin_amdgcn_s_barrier();
    const unsigned short* Ab = &As[0][aro];
    const unsigned short* Bb = &Bs[0][bro];
    bf16x8 af[4], bfr[8];
    #pragma unroll
    for (int mt = 0; mt < 4; mt++)
      af[mt] = *(const bf16x8*)(Ab + mt * 512);
    #pragma unroll
    for (int nt = 0; nt < 8; nt++)
      bfr[nt] = *(const bf16x8*)(Bb + nt * 512);
    #pragma unroll
    for (int mt = 0; mt < 4; mt++)
      #pragma unroll
      for (int nt = 0; nt < 8; nt++)
        acc[mt][nt] = MFMA(af[mt], bfr[nt], acc[mt][nt], 0, 0, 0);
  }

  // epilogue: + cc -> outT[r][b][o] bf16
  #pragma unroll
  for (int mt = 0; mt < 4; mt++) {
    int ob = mh * 64 + mt * 16 + quad * 4;
    f32x4 cv = *(const f32x4*)(params + 384 + ob);
    #pragma unroll
    for (int nt = 0; nt < 8; nt++) {
      int col = b0 + nh * 128 + nt * 16 + nl;
      f32x4 a = acc[mt][nt];
      us4 w;
      w.x = f2bf(a[0] + cv[0]);
      w.y = f2bf(a[1] + cv[1]);
      w.z = f2bf(a[2] + cv[2]);
      w.w = f2bf(a[3] + cv[3]);
      *(us4*)(outT + (r * 2048 + col) * 128 + ob) = w;
    }
  }
}

// ---- transpose-out: outT[r][b][o] bf16 -> out[b][o][r] f32
__global__ __launch_bounds__(256) void t_out(const unsigned short* __restrict__ outT,
                                             float* __restrict__ out) {
  __shared__ float ot[60 * 129];
  const int b = blockIdx.x, t = threadIdx.x;
  for (int i = t; i < 1920; i += 256) {
    int r = i >> 5, og = (i & 31) << 2;
    us4 v = *(const us4*)(outT + (r * 2048 + b) * 128 + og);
    ot[r * 129 + og + 0] = bf2f(v.x);
    ot[r * 129 + og + 1] = bf2f(v.y);
    ot[r * 129 + og + 2] = bf2f(v.z);
    ot[r * 129 + og + 3] = bf2f(v.w);
  }
  __syncthreads();
  int o = t >> 1, s = t & 1;
  float* dst = out + b * 7680 + o * 60 + s * 30;
  #pragma unroll
  for (int j = 0; j < 30; j++) dst[j] = ot[(s * 30 + j) * 129 + o];
}

extern "C" void kernel_launch(void* const* d_in, const int* in_sizes, int n_in,
                              void* d_out, int out_size, void* d_ws, size_t ws_size,
                              hipStream_t stream) {
  const float* x   = (const float*)d_in[0];
  const int*   nei = (const int*)d_in[1];
  const float* g1  = (const float*)d_in[2];
  const float* be1 = (const float*)d_in[3];
  const float* mu1 = (const float*)d_in[4];
  const float* va1 = (const float*)d_in[5];
  const float* W1  = (const float*)d_in[6];
  const float* c1  = (const float*)d_in[7];
  const float* g2  = (const float*)d_in[8];
  const float* be2 = (const float*)d_in[9];
  const float* mu2 = (const float*)d_in[10];
  const float* va2 = (const float*)d_in[11];
  const float* W2  = (const float*)d_in[12];
  const float* c2  = (const float*)d_in[13];
  const float* g3  = (const float*)d_in[14];
  const float* be3 = (const float*)d_in[15];
  const float* mu3 = (const float*)d_in[16];
  const float* va3 = (const float*)d_in[17];
  const float* W3  = (const float*)d_in[18];
  const float* c3  = (const float*)d_in[19];

  // ws layout (63.5 MB): W1t | W23t | params | z2T | z3T | big(z1T ∪ outT)
  unsigned short* W1t  = (unsigned short*)d_ws;
  unsigned short* W23t = W1t + 53248;
  float*          prm  = (float*)(W23t + 212992);
  unsigned short* z2T  = (unsigned short*)(prm + 512);
  unsigned short* z3T  = z2T + ZTOT;
  unsigned short* big  = z3T + ZTOT;       // z1T (read in gemm1) aliases outT (written in gemm2)
  unsigned short* z1T  = big;
  unsigned short* outT = big;

  prep_w<<<80, 256, 0, stream>>>(W1, W2, W3,
                                 g1, be1, mu1, va1, c1,
                                 g2, be2, mu2, va2, c2,
                                 g3, be3, mu3, va3, c3,
                                 W1t, W23t, prm);
  t_in<<<2048, 256, 0, stream>>>(x, prm, z1T, z3T);
  gemm1<<<480, 256, 0, stream>>>(W1t, z1T, nei, prm, z2T);
  gemm2<<<480, 256, 0, stream>>>(W23t, z2T, z3T, nei, prm, outT);
  t_out<<<2048, 256, 0, stream>>>(outT, (float*)d_out);
}

// Round 6
// 224.213 us; speedup vs baseline: 1.6633x; 1.0498x over previous
//
#include <hip/hip_runtime.h>
#include <hip/hip_bf16.h>

// Residual_Comb_Conv: B=2048, C_IN=64, C_MID=64, C_OUT=128, R=60, K=13
// R12: gemm2 frozen at the R11 structure (63 us, MfmaUtil 33, 0 conflicts).
// The remaining ~170 us is the non-gemm2 pool; this round:
//  - gemm1 ported to the proven gemm2 template: block = (r, btile=256 b),
//    C[64x256], 4 waves each owning a 64x64 column slice (A-fragments shared),
//    BK=32 x 26 steps, triple-buffered 60 KB (2 blocks/CU), gl16 staging with
//    the verified source-side XOR swizzle, two-barrier counted-vmcnt(5)
//    phases + setprio. Replaces the old reg-staged 2-phase (full drains x13).
//  - t_out phase 2 store-coalesced: thread t writes out[b*7680 + i] for
//    i = t..7680 step 256 (lane-consecutive addresses) instead of 30 scalar
//    stores at 120 B lane stride; LDS reads stride 129 = conflict-free.

typedef __attribute__((ext_vector_type(8))) short bf16x8;
typedef __attribute__((ext_vector_type(4))) float f32x4;
typedef __attribute__((ext_vector_type(4))) unsigned short us4;
typedef __attribute__((ext_vector_type(8))) unsigned short us8;

#define EPSV 1e-5f
#define PLANE 131072           // 2048*64 shorts per z plane
#define ZTOT  7864320          // 60*PLANE

__device__ __forceinline__ unsigned short f2bf(float f) {
  unsigned int u = __builtin_bit_cast(unsigned int, f);
  u += 0x7FFFu + ((u >> 16) & 1u);   // round-to-nearest-even
  return (unsigned short)(u >> 16);
}
__device__ __forceinline__ float bf2f(unsigned short s) {
  unsigned int u = ((unsigned int)s) << 16;
  return __builtin_bit_cast(float, u);
}

// async global->LDS, 16B per lane, wave-uniform LDS base + lane*16 linear dest
typedef const __attribute__((address_space(1))) unsigned int gas_u32;
typedef __attribute__((address_space(3))) unsigned int las_u32;
__device__ __forceinline__ void gl16(const void* g, void* l) {
  __builtin_amdgcn_global_load_lds((gas_u32*)g, (las_u32*)l, 16, 0, 0);
}

// ---- prep: weights -> bf16 transposed layouts; last block also folds BN params
// params: [a1|b1|a3|b3|a2|b2p] (6*64) + cc (128) = 512 floats
__global__ void prep_w(const float* __restrict__ W1, const float* __restrict__ W2,
                       const float* __restrict__ W3,
                       const float* __restrict__ g1, const float* __restrict__ be1,
                       const float* __restrict__ mu1, const float* __restrict__ va1,
                       const float* __restrict__ c1,
                       const float* __restrict__ g2, const float* __restrict__ be2,
                       const float* __restrict__ mu2, const float* __restrict__ va2,
                       const float* __restrict__ c2,
                       const float* __restrict__ g3, const float* __restrict__ be3,
                       const float* __restrict__ mu3, const float* __restrict__ va3,
                       const float* __restrict__ c3,
                       unsigned short* __restrict__ W1t,
                       unsigned short* __restrict__ W23t,
                       float* __restrict__ params) {
  int t = blockIdx.x * 256 + threadIdx.x;
  if (t < 4096) {                        // W1: 64*64 (o,c) rows
    int o = t >> 6, c = t & 63;
    const float* src = W1 + (o * 64 + c) * 13;
    unsigned short* dst = W1t + o * 832 + c;
    #pragma unroll
    for (int ks = 0; ks < 13; ks++) dst[ks * 64] = f2bf(src[ks]);
  } else if (t < 20480) {                // W2,W3: 2*128*64 rows
    int idx = t - 4096;
    int half = idx >> 13;                // 0 -> W2, 1 -> W3
    int o = (idx >> 6) & 127, c = idx & 63;
    const float* src = (half ? W3 : W2) + (o * 64 + c) * 13;
    unsigned short* dst = W23t + o * 1664 + half * 13 * 64 + c;
    #pragma unroll
    for (int ks = 0; ks < 13; ks++) dst[ks * 64] = f2bf(src[ks]);
  }
  if (blockIdx.x == 79) {
    int u = threadIdx.x;
    if (u < 64) {
      float a1v = g1[u] * rsqrtf(va1[u] + EPSV);
      params[u]       = a1v;
      params[64 + u]  = be1[u] - mu1[u] * a1v;
      float a3v = g3[u] * rsqrtf(va3[u] + EPSV);
      params[128 + u] = a3v;
      params[192 + u] = be3[u] - mu3[u] * a3v;
      float a2v = g2[u] * rsqrtf(va2[u] + EPSV);
      params[256 + u] = a2v;
      params[320 + u] = be2[u] - mu2[u] * a2v + a2v * c1[u];  // fold conv1 bias
    }
    if (u < 128) params[384 + u] = c2[u] + c3[u];
  }
}

// ---- transpose-in: x[b][c][r] f32 -> z1T/z3T[r][b][c] bf16 with act1/act3
__global__ __launch_bounds__(256) void t_in(const float* __restrict__ x,
                                            const float* __restrict__ params,
                                            unsigned short* __restrict__ z1T,
                                            unsigned short* __restrict__ z3T) {
  __shared__ float xt[64 * 61];
  __shared__ float prm[256];
  const int b = blockIdx.x, t = threadIdx.x;
  prm[t] = params[t];                       // a1|b1|a3|b3
  for (int i = t; i < 3840; i += 256) {
    int c = i / 60;
    xt[c * 61 + (i - c * 60)] = x[b * 3840 + i];
  }
  __syncthreads();
  if (t < 240) {
    int r = t >> 2, g = t & 3, c0 = g << 4;
    us8 z1v0, z1v1, z3v0, z3v1;
    #pragma unroll
    for (int j = 0; j < 8; j++) {
      int c = c0 + j;
      float v = xt[c * 61 + r];
      z1v0[j] = f2bf(fmaxf(fmaf(v, prm[c], prm[64 + c]), 0.f));
      z3v0[j] = f2bf(fmaxf(fmaf(v, prm[128 + c], prm[192 + c]), 0.f));
    }
    #pragma unroll
    for (int j = 0; j < 8; j++) {
      int c = c0 + 8 + j;
      float v = xt[c * 61 + r];
      z1v1[j] = f2bf(fmaxf(fmaf(v, prm[c], prm[64 + c]), 0.f));
      z3v1[j] = f2bf(fmaxf(fmaf(v, prm[128 + c], prm[192 + c]), 0.f));
    }
    int idx = (r * 2048 + b) * 64 + c0;
    *(us8*)(z1T + idx) = z1v0;  *(us8*)(z1T + idx + 8) = z1v1;
    *(us8*)(z3T + idx) = z3v0;  *(us8*)(z3T + idx + 8) = z3v1;
  }
}

#define MFMA __builtin_amdgcn_mfma_f32_16x16x32_bf16

// ---- gemm1: block = (r, btile=256 b): C[64 x 256] = W1t[64x832] . z1T-panels.
//      4 waves, each owns cols wv*64..wv*64+63 (4m x 4n of 16x16x32); A
//      fragments shared by all waves. BK=32, 26 steps, triple-buffered 60 KB.
//      Same two-barrier counted-vmcnt phase discipline as gemm2 (R11).
__global__ __launch_bounds__(256, 2) void gemm1(const unsigned short* __restrict__ W1t,
                                                const unsigned short* __restrict__ z1T,
                                                const int* __restrict__ nei,
                                                const float* __restrict__ params,
                                                unsigned short* __restrict__ z2T) {
  __shared__ unsigned short As[3][2048];     // 64 rows x 32 shorts per buf (4 KB)
  __shared__ unsigned short Bs[3][8192];     // 256 rows x 32 shorts per buf (16 KB)
  __shared__ int sOff[13];                   // per-plane byte offsets into z1T

  const int bid = blockIdx.x;
  const int r = bid >> 3, btile = bid & 7;   // bid%8 = btile -> one btile per XCD
  const int b0 = btile << 8;
  const int t = threadIdx.x, wv = t >> 6, lane = t & 63;
  const int quad = lane >> 4, nl = lane & 15;

  if (t < 13) sOff[t] = nei[r * 13 + t] * (PLANE * 2);

  // staging: slab = 16 rows x 64 B = one gl16 per wave.
  // lane -> (lr = lane>>2, chunk lj = lane&3); source chunk lj ^ ((lr>>1)&3).
  const int lr = lane >> 2, lj = lane & 3;
  const int sj = ((lj ^ ((lr >> 1) & 3)) << 4);
  // A: 4 slabs (64 rows); wave wv stages slab wv (rows 16wv..16wv+15).
  const int aoff = (16 * wv + lr) * 1664 + sj;     // W1t row stride 832 shorts
  // B: 16 slabs (256 rows); wave wv stages slabs 4wv..4wv+3 (its own cols).
  int boff[4];
  #pragma unroll
  for (int i = 0; i < 4; i++) boff[i] = (b0 + 16 * (4 * wv + i) + lr) * 128 + sj;

  const char* gAb = (const char*)W1t;
  const char* z1b = (const char*)z1T;

  __syncthreads();                           // sOff visible

  // prologue: stage kn=0 -> buf0, kn=1 -> buf1 (plane 0, halves 0/1)
  {
    const char* gb = z1b + sOff[0];
    gl16(gAb + aoff, &As[0][wv * 512]);
    #pragma unroll
    for (int i = 0; i < 4; i++) gl16(gb + boff[i], &Bs[0][(4 * wv + i) * 512]);
    gl16(gAb + 64 + aoff, &As[1][wv * 512]);
    #pragma unroll
    for (int i = 0; i < 4; i++) gl16(gb + 64 + boff[i], &Bs[1][(4 * wv + i) * 512]);
  }
  asm volatile("s_waitcnt vmcnt(5)" ::: "memory");   // own stage-0 landed
  __builtin_amdgcn_s_barrier();

  const int rc = ((quad ^ ((nl >> 1) & 3)) << 3);    // read-side swizzled chunk
  const int aro = nl * 32 + rc;
  const int bro = (wv * 64 + nl) * 32 + rc;

  f32x4 acc[4][4] = {};
  int cb = 0, sb = 2;
  #pragma unroll 1
  for (int s = 0; s < 25; s++) {
    const unsigned short* Ab = &As[cb][aro];
    const unsigned short* Bb = &Bs[cb][bro];
    bf16x8 af[4], bfr[4];
    #pragma unroll
    for (int mt = 0; mt < 4; mt++)
      af[mt] = *(const bf16x8*)(Ab + mt * 512);
    #pragma unroll
    for (int nt = 0; nt < 4; nt++)
      bfr[nt] = *(const bf16x8*)(Bb + nt * 512);
    const int kn = s + 2;
    if (kn < 26) {
      const int pn = kn >> 1;
      int off = sOff[pn] + ((kn & 1) << 6);
      const char* ga = gAb + kn * 64;
      const char* gb = z1b + off;
      gl16(ga + aoff, &As[sb][wv * 512]);
      #pragma unroll
      for (int i = 0; i < 4; i++) gl16(gb + boff[i], &Bs[sb][(4 * wv + i) * 512]);
    }
    __builtin_amdgcn_s_barrier();                      // b1
    asm volatile("s_waitcnt lgkmcnt(0)" ::: "memory");
    __builtin_amdgcn_sched_barrier(0);
    __builtin_amdgcn_s_setprio(1);
    #pragma unroll
    for (int mt = 0; mt < 4; mt++)
      #pragma unroll
      for (int nt = 0; nt < 4; nt++)
        acc[mt][nt] = MFMA(af[mt], bfr[nt], acc[mt][nt], 0, 0, 0);
    __builtin_amdgcn_s_setprio(0);
    __builtin_amdgcn_sched_barrier(0);
    asm volatile("s_waitcnt vmcnt(5)" ::: "memory");   // stage(s+1) landed (own)
    __builtin_amdgcn_s_barrier();                      // b2
    cb = (cb == 2) ? 0 : cb + 1;
    sb = (sb == 2) ? 0 : sb + 1;
  }
  // peeled last step (s=25, cb=1)
  {
    asm volatile("s_waitcnt vmcnt(0)" ::: "memory");
    __builtin_amdgcn_s_barrier();
    const unsigned short* Ab = &As[1][aro];
    const unsigned short* Bb = &Bs[1][bro];
    bf16x8 af[4], bfr[4];
    #pragma unroll
    for (int mt = 0; mt < 4; mt++)
      af[mt] = *(const bf16x8*)(Ab + mt * 512);
    #pragma unroll
    for (int nt = 0; nt < 4; nt++)
      bfr[nt] = *(const bf16x8*)(Bb + nt * 512);
    #pragma unroll
    for (int mt = 0; mt < 4; mt++)
      #pragma unroll
      for (int nt = 0; nt < 4; nt++)
        acc[mt][nt] = MFMA(af[mt], bfr[nt], acc[mt][nt], 0, 0, 0);
  }

  // epilogue: act2 -> z2T[r][b][o]
  #pragma unroll
  for (int mt = 0; mt < 4; mt++) {
    int ob = mt * 16 + quad * 4;
    f32x4 av = *(const f32x4*)(params + 256 + ob);
    f32x4 bv = *(const f32x4*)(params + 320 + ob);
    #pragma unroll
    for (int nt = 0; nt < 4; nt++) {
      int col = b0 + wv * 64 + nt * 16 + nl;
      f32x4 a = acc[mt][nt];
      us4 w;
      w.x = f2bf(fmaxf(fmaf(a[0], av[0], bv[0]), 0.f));
      w.y = f2bf(fmaxf(fmaf(a[1], av[1], bv[1]), 0.f));
      w.z = f2bf(fmaxf(fmaf(a[2], av[2], bv[2]), 0.f));
      w.w = f2bf(fmaxf(fmaf(a[3], av[3], bv[3]), 0.f));
      *(us4*)(z2T + (r * 2048 + col) * 64 + ob) = w;
    }
  }
}

// ---- gemm2: block = (btile=256 batches, r): C[128 x 256], 4 waves (2mh x 2nh),
//      wave tile 64 x 128 = 4m x 8n. BK=32, 52 K-steps, triple-buffered.
//      m201-style phases: {ds_read cur || stage s+2} b1 lgkm(0) setprio MFMA
//      setprio(0) vmcnt(6) b2. Counted vmcnt before b2 certifies stage(s+1)
//      block-wide before anyone reads it.
__global__ __launch_bounds__(256, 2) void gemm2(const unsigned short* __restrict__ W23t,
                                                const unsigned short* __restrict__ z2T,
                                                const unsigned short* __restrict__ z3T,
                                                const int* __restrict__ nei,
                                                const float* __restrict__ params,
                                                unsigned short* __restrict__ outT) {
  __shared__ unsigned short As[3][4096];     // 128 rows x 32 shorts per buf (8 KB)
  __shared__ unsigned short Bs[3][8192];     // 256 rows x 32 shorts per buf (16 KB)
  __shared__ int sOff[26];                   // per-plane byte offsets from z2T

  const int bid = blockIdx.x;
  const int r = bid >> 3, btile = bid & 7;   // bid%8 = btile -> one btile per XCD
  const int b0 = btile << 8;
  const int t = threadIdx.x, wv = t >> 6, lane = t & 63;
  const int quad = lane >> 4, nl = lane & 15;
  const int mh = wv >> 1, nh = wv & 1;

  if (t < 26) {
    int idx = t < 13 ? t : t - 13;
    int p = nei[r * 13 + idx];
    sOff[t] = p * (PLANE * 2) + (t < 13 ? 0 : ZTOT * 2);
  }

  // staging geometry: slab = 16 rows x 64 B = 1 KB = one gl16 per wave.
  // lane -> (slab-row lr = lane>>2, chunk lj = lane&3); source chunk
  // pre-swizzled lj ^ ((lr>>1)&3) so the (linear-dest) LDS ends up swizzled.
  const int lr = lane >> 2, lj = lane & 3;
  const int sj = ((lj ^ ((lr >> 1) & 3)) << 4);   // byte offset in source row
  // A: 8 slabs (128 rows); wave wv owns slabs 2wv, 2wv+1.
  int aoff[2];
  #pragma unroll
  for (int i = 0; i < 2; i++) aoff[i] = (16 * (2 * wv + i) + lr) * 3328 + sj;
  // B: 16 slabs (256 rows); wave wv owns slabs 4wv..4wv+3.
  int boff[4];
  #pragma unroll
  for (int i = 0; i < 4; i++) boff[i] = (b0 + 16 * (4 * wv + i) + lr) * 128 + sj;

  const char* gAb = (const char*)W23t;
  const char* z2b = (const char*)z2T;

  __syncthreads();                           // sOff visible

  // prologue: stage kn=0 -> buf0, kn=1 -> buf1 (plane 0, halves 0/1)
  {
    const char* gb = z2b + sOff[0];
    #pragma unroll
    for (int i = 0; i < 2; i++) gl16(gAb + aoff[i], &As[0][(2 * wv + i) * 512]);
    #pragma unroll
    for (int i = 0; i < 4; i++) gl16(gb + boff[i], &Bs[0][(4 * wv + i) * 512]);
    #pragma unroll
    for (int i = 0; i < 2; i++) gl16(gAb + 64 + aoff[i], &As[1][(2 * wv + i) * 512]);
    #pragma unroll
    for (int i = 0; i < 4; i++) gl16(gb + 64 + boff[i], &Bs[1][(4 * wv + i) * 512]);
  }
  asm volatile("s_waitcnt vmcnt(6)" ::: "memory");   // own stage-0 landed
  __builtin_amdgcn_s_barrier();                      // everyone's stage-0 landed

  const int rc = ((quad ^ ((nl >> 1) & 3)) << 3);  // read-side swizzled chunk (shorts)
  const int aro = (mh * 64 + nl) * 32 + rc;
  const int bro = (nh * 128 + nl) * 32 + rc;

  f32x4 acc[4][8] = {};
  int cb = 0, sb = 2;                        // compute buf = s%3, stage buf = (s+2)%3
  #pragma unroll 1
  for (int s = 0; s < 51; s++) {
    // R1: ds_read current buf + issue stage(s+2)
    const unsigned short* Ab = &As[cb][aro];
    const unsigned short* Bb = &Bs[cb][bro];
    bf16x8 af[4], bfr[8];
    #pragma unroll
    for (int mt = 0; mt < 4; mt++)
      af[mt] = *(const bf16x8*)(Ab + mt * 512);
    #pragma unroll
    for (int nt = 0; nt < 8; nt++)
      bfr[nt] = *(const bf16x8*)(Bb + nt * 512);
    const int kn = s + 2;
    if (kn < 52) {
      const int pn = kn >> 1;
      int off = sOff[pn] + ((kn & 1) << 6);
      const char* ga = gAb + kn * 64;
      const char* gb = z2b + off;
      #pragma unroll
      for (int i = 0; i < 2; i++) gl16(ga + aoff[i], &As[sb][(2 * wv + i) * 512]);
      #pragma unroll
      for (int i = 0; i < 4; i++) gl16(gb + boff[i], &Bs[sb][(4 * wv + i) * 512]);
    }
    __builtin_amdgcn_s_barrier();                      // b1: all reads issued
    asm volatile("s_waitcnt lgkmcnt(0)" ::: "memory"); // frags in registers
    __builtin_amdgcn_sched_barrier(0);
    __builtin_amdgcn_s_setprio(1);
    #pragma unroll
    for (int mt = 0; mt < 4; mt++)
      #pragma unroll
      for (int nt = 0; nt < 8; nt++)
        acc[mt][nt] = MFMA(af[mt], bfr[nt], acc[mt][nt], 0, 0, 0);
    __builtin_amdgcn_s_setprio(0);
    __builtin_amdgcn_sched_barrier(0);
    asm volatile("s_waitcnt vmcnt(6)" ::: "memory");   // stage(s+1) landed (own)
    __builtin_amdgcn_s_barrier();                      // b2: landed block-wide
    cb = (cb == 2) ? 0 : cb + 1;
    sb = (sb == 2) ? 0 : sb + 1;
  }
  // peeled last step (s=51, cb=0): stage-51 certified via vmcnt(0)+barrier
  {
    asm volatile("s_waitcnt vmcnt(0)" ::: "memory");
    __builtin_amdgcn_s_barrier();
    const unsigned short* Ab = &As[0][aro];
    const unsigned short* Bb = &Bs[0][bro];
    bf16x8 af[4], bfr[8];
    #pragma unroll
    for (int mt = 0; mt < 4; mt++)
      af[mt] = *(const bf16x8*)(Ab + mt * 512);
    #pragma unroll
    for (int nt = 0; nt < 8; nt++)
      bfr[nt] = *(const bf16x8*)(Bb + nt * 512);
    #pragma unroll
    for (int mt = 0; mt < 4; mt++)
      #pragma unroll
      for (int nt = 0; nt < 8; nt++)
        acc[mt][nt] = MFMA(af[mt], bfr[nt], acc[mt][nt], 0, 0, 0);
  }

  // epilogue: + cc -> outT[r][b][o] bf16
  #pragma unroll
  for (int mt = 0; mt < 4; mt++) {
    int ob = mh * 64 + mt * 16 + quad * 4;
    f32x4 cv = *(const f32x4*)(params + 384 + ob);
    #pragma unroll
    for (int nt = 0; nt < 8; nt++) {
      int col = b0 + nh * 128 + nt * 16 + nl;
      f32x4 a = acc[mt][nt];
      us4 w;
      w.x = f2bf(a[0] + cv[0]);
      w.y = f2bf(a[1] + cv[1]);
      w.z = f2bf(a[2] + cv[2]);
      w.w = f2bf(a[3] + cv[3]);
      *(us4*)(outT + (r * 2048 + col) * 128 + ob) = w;
    }
  }
}

// ---- transpose-out: outT[r][b][o] bf16 -> out[b][o][r] f32
//      phase 2 store-coalesced: thread t writes out[b*7680+i], i=t..7680:256
//      (lane-consecutive addresses); LDS read stride 129 == 1 mod 32 -> free.
__global__ __launch_bounds__(256) void t_out(const unsigned short* __restrict__ outT,
                                             float* __restrict__ out) {
  __shared__ float ot[60 * 129];
  const int b = blockIdx.x, t = threadIdx.x;
  for (int i = t; i < 1920; i += 256) {
    int r = i >> 5, og = (i & 31) << 2;
    us4 v = *(const us4*)(outT + (r * 2048 + b) * 128 + og);
    ot[r * 129 + og + 0] = bf2f(v.x);
    ot[r * 129 + og + 1] = bf2f(v.y);
    ot[r * 129 + og + 2] = bf2f(v.z);
    ot[r * 129 + og + 3] = bf2f(v.w);
  }
  __syncthreads();
  float* dst = out + b * 7680;
  for (int i = t; i < 7680; i += 256) {
    int o = i / 60, r = i - o * 60;
    dst[i] = ot[r * 129 + o];
  }
}

extern "C" void kernel_launch(void* const* d_in, const int* in_sizes, int n_in,
                              void* d_out, int out_size, void* d_ws, size_t ws_size,
                              hipStream_t stream) {
  const float* x   = (const float*)d_in[0];
  const int*   nei = (const int*)d_in[1];
  const float* g1  = (const float*)d_in[2];
  const float* be1 = (const float*)d_in[3];
  const float* mu1 = (const float*)d_in[4];
  const float* va1 = (const float*)d_in[5];
  const float* W1  = (const float*)d_in[6];
  const float* c1  = (const float*)d_in[7];
  const float* g2  = (const float*)d_in[8];
  const float* be2 = (const float*)d_in[9];
  const float* mu2 = (const float*)d_in[10];
  const float* va2 = (const float*)d_in[11];
  const float* W2  = (const float*)d_in[12];
  const float* c2  = (const float*)d_in[13];
  const float* g3  = (const float*)d_in[14];
  const float* be3 = (const float*)d_in[15];
  const float* mu3 = (const float*)d_in[16];
  const float* va3 = (const float*)d_in[17];
  const float* W3  = (const float*)d_in[18];
  const float* c3  = (const float*)d_in[19];

  // ws layout (63.5 MB): W1t | W23t | params | z2T | z3T | big(z1T ∪ outT)
  unsigned short* W1t  = (unsigned short*)d_ws;
  unsigned short* W23t = W1t + 53248;
  float*          prm  = (float*)(W23t + 212992);
  unsigned short* z2T  = (unsigned short*)(prm + 512);
  unsigned short* z3T  = z2T + ZTOT;
  unsigned short* big  = z3T + ZTOT;       // z1T (read in gemm1) aliases outT (written in gemm2)
  unsigned short* z1T  = big;
  unsigned short* outT = big;

  prep_w<<<80, 256, 0, stream>>>(W1, W2, W3,
                                 g1, be1, mu1, va1, c1,
                                 g2, be2, mu2, va2, c2,
                                 g3, be3, mu3, va3, c3,
                                 W1t, W23t, prm);
  t_in<<<2048, 256, 0, stream>>>(x, prm, z1T, z3T);
  gemm1<<<480, 256, 0, stream>>>(W1t, z1T, nei, prm, z2T);
  gemm2<<<480, 256, 0, stream>>>(W23t, z2T, z3T, nei, prm, outT);
  t_out<<<2048, 256, 0, stream>>>(outT, (float*)d_out);
}